// Round 7
// baseline (396.238 us; speedup 1.0000x reference)
//
#include <hip/hip_runtime.h>
#include <hip/hip_bf16.h>
#include <math.h>

// Problem constants (B=4, Cin=256, Cout=128, H=W=64)
#define NB 4
#define CI 256
#define CO 128
#define HW 4096

typedef __attribute__((ext_vector_type(8))) short s8v;   // 8 bf16 = 4 VGPRs (MFMA A/B frag)
typedef __attribute__((ext_vector_type(4))) short s4v;
typedef __attribute__((ext_vector_type(4))) float f4v;   // MFMA C/D frag

__device__ __forceinline__ unsigned short f2bf(float f){
    __hip_bfloat16 h = __float2bfloat16(f);   // RNE
    return *reinterpret_cast<unsigned short*>(&h);
}

// async global->LDS DMA, 16B per lane; LDS dest = wave-uniform base + lane*16
__device__ __forceinline__ void lds_dma16(const void* g, void* l){
    __builtin_amdgcn_global_load_lds((const __attribute__((address_space(1))) unsigned int*)g,
                                     (__attribute__((address_space(3))) unsigned int*)l,
                                     16, 0, 0);
}

// A&S 7.1.26 erf (max abs err 1.5e-7)
__device__ __forceinline__ float gelu_f(float x){
    float z  = x * 0.70710678118654752f;
    float az = fabsf(z);
    float tt = 1.f / (1.f + 0.3275911f * az);
    float poly = tt*(0.254829592f + tt*(-0.284496736f + tt*(1.421413741f +
                 tt*(-1.453152027f + tt*1.061405429f))));
    float erfv = 1.f - poly * __expf(-az*az);
    erfv = (z < 0.f) ? -erfv : erfv;
    return 0.5f * x * (1.f + erfv);
}

// ---------------- fused: per-channel avg/max (blocks 0..1023) + ALL weight casts ----------------
__global__ void k_pre(const float* __restrict__ x, float* __restrict__ avg, float* __restrict__ mx,
                      const float* __restrict__ c1, const float* __restrict__ a0,
                      const float* __restrict__ pj, const float* __restrict__ c2,
                      const float* __restrict__ d3, const float* __restrict__ d6,
                      const float* __restrict__ d9,
                      unsigned short* __restrict__ w_c1, unsigned short* __restrict__ w_a0,
                      unsigned short* __restrict__ w_pj, unsigned short* __restrict__ w_c2,
                      unsigned short* __restrict__ w_d3, unsigned short* __restrict__ w_d6,
                      unsigned short* __restrict__ w_d9){
    int blk = blockIdx.x;
    int t = threadIdx.x;
    if (blk < 1024){
        const float* p = x + (long long)blk * HW;
        float s = 0.f, m = -1e30f;
        for (int i = t; i < HW; i += 256){ float v = p[i]; s += v; m = fmaxf(m, v); }
        __shared__ float ss[256], sm[256];
        ss[t] = s; sm[t] = m; __syncthreads();
        for (int o = 128; o > 0; o >>= 1){
            if (t < o){ ss[t] += ss[t+o]; sm[t] = fmaxf(sm[t], sm[t+o]); }
            __syncthreads();
        }
        if (t == 0){ avg[blk] = ss[0] / (float)HW; mx[blk] = sm[0]; }
        return;
    }
    int i = (blk - 1024)*256 + t;
    if (i < 458752){
        if (i < 32768)        w_c1[i]        = f2bf(c1[i]);
        else if (i < 98304)   w_a0[i-32768]  = f2bf(a0[i-32768]);
        else if (i < 425984)  w_pj[i-98304]  = f2bf(pj[i-98304]);
        else                  w_c2[i-425984] = f2bf(c2[i-425984]);
    } else {
        int j = i - 458752;
        int which = j / 589824;
        int l = j - which*589824;
        int tap = l >> 16, rem = l & 65535, o = rem >> 8, ci = rem & 255;
        const float* src = (which==0) ? d3 : ((which==1) ? d6 : d9);
        unsigned short* dst = (which==0) ? w_d3 : ((which==1) ? w_d6 : w_d9);
        dst[l] = f2bf(src[o*2304 + ci*9 + tap]);
    }
}

// ---------------- ChannelWeighting; also gp = avg*(1+s); block 0 zeroes the DMA zero-page ----------------
__global__ void k_cw(const float* __restrict__ avg, const float* __restrict__ mx,
                     const float* __restrict__ w1, const float* __restrict__ b1,
                     const float* __restrict__ lng, const float* __restrict__ lnb,
                     const float* __restrict__ w2, const float* __restrict__ b2,
                     float* __restrict__ sv, float* __restrict__ gp,
                     float* __restrict__ zb){
    int b = blockIdx.x, t = threadIdx.x;
    if (b == 0) zb[t] = 0.f;                 // 1 KB zero-page for OOB DMA lanes
    __shared__ float o_s[256];
    __shared__ float h_s[128];
    __shared__ float stat[2];
    float a = avg[b*256 + t];
    o_s[t] = fabsf(a - mx[b*256 + t]) * a;
    __syncthreads();
    if (t < 128){
        float h = b1[t];
        for (int i = 0; i < 256; i++) h += o_s[i] * w1[t*256 + i];
        h_s[t] = h;
    }
    __syncthreads();
    if (t == 0){
        float s = 0.f, s2 = 0.f;
        for (int j = 0; j < 128; j++){ s += h_s[j]; s2 += h_s[j]*h_s[j]; }
        float mean = s / 128.f;
        float var  = s2 / 128.f - mean*mean;
        stat[0] = mean; stat[1] = rsqrtf(var + 1e-5f);
    }
    __syncthreads();
    if (t < 128) h_s[t] = lng[t] * ((h_s[t] - stat[0]) * stat[1]) + lnb[t];
    __syncthreads();
    float z = b2[t];
    for (int j = 0; j < 128; j++) z += h_s[j] * w2[t*128 + j];
    float sig = 1.f / (1.f + __expf(-z));
    sv[b*256 + t] = sig;
    gp[b*256 + t] = a * (1.f + sig);
}

// ---------------- x -> xT bf16 [b][HW][256] and xcT = bf16(x*(1+s)) ----------------
__global__ void k_xT(const float* __restrict__ x, const float* __restrict__ sv,
                     unsigned short* __restrict__ xT, unsigned short* __restrict__ xcT){
    int b = blockIdx.z, c0 = blockIdx.y*64, h0 = blockIdx.x*64;
    __shared__ unsigned short T1[64][66], T2[64][66];
    int t = threadIdx.x;
    int hl = t & 63, cs = t >> 6;
    #pragma unroll
    for (int r = 0; r < 16; r++){
        int c = cs*16 + r;
        float v = x[((long long)b*256 + c0 + c)*HW + h0 + hl];
        float sc = 1.f + sv[b*256 + c0 + c];
        T1[c][hl] = f2bf(v);
        T2[c][hl] = f2bf(v*sc);
    }
    __syncthreads();
    int cl = t & 63, hs = t >> 6;
    #pragma unroll
    for (int r = 0; r < 16; r++){
        int h = hs*16 + r;
        long long o = ((long long)b*HW + h0 + h)*256 + c0 + cl;
        xT[o]  = T1[cl][h];
        xcT[o] = T2[cl][h];
    }
}

// ============ 8-wave epilogue, N=32: LN(256ch)+GELU -> transposed bf16 ============
__device__ __forceinline__ void ln_epi32(f4v acc[2][2],
        int b, int n0, int w, int lane, int m, int q, int t,
        const float* Gs, const float* Bts,
        float (*Psum)[32], float (*Psq)[32], float* Mn, float* Iv,
        unsigned short* __restrict__ outT, int outPitch, int colOff){
    float ls[2], ls2[2];
    #pragma unroll
    for (int ct = 0; ct < 2; ct++){
        float s = 0.f, s2 = 0.f;
        #pragma unroll
        for (int ms = 0; ms < 2; ms++)
            #pragma unroll
            for (int r = 0; r < 4; r++){ float v = acc[ms][ct][r]; s += v; s2 += v*v; }
        ls[ct] = s; ls2[ct] = s2;
    }
    #pragma unroll
    for (int ct = 0; ct < 2; ct++){
        ls[ct]  += __shfl_xor(ls[ct], 16);  ls[ct]  += __shfl_xor(ls[ct], 32);
        ls2[ct] += __shfl_xor(ls2[ct], 16); ls2[ct] += __shfl_xor(ls2[ct], 32);
    }
    if (lane < 16){
        #pragma unroll
        for (int ct = 0; ct < 2; ct++){ Psum[w][ct*16+lane] = ls[ct]; Psq[w][ct*16+lane] = ls2[ct]; }
    }
    __syncthreads();
    if (t < 32){
        float s = 0.f, s2 = 0.f;
        #pragma unroll
        for (int ww = 0; ww < 8; ww++){ s += Psum[ww][t]; s2 += Psq[ww][t]; }
        float mean = s * (1.f/256.f);
        Mn[t] = mean;
        Iv[t] = rsqrtf(s2*(1.f/256.f) - mean*mean + 1e-6f);
    }
    __syncthreads();
    #pragma unroll
    for (int ct = 0; ct < 2; ct++){
        int p = ct*16 + m;
        float mean = Mn[p], inv = Iv[p];
        long long rowb = ((long long)b*HW + n0 + p)*outPitch + colOff;
        #pragma unroll
        for (int ms = 0; ms < 2; ms++){
            s4v o4;
            #pragma unroll
            for (int r = 0; r < 4; r++){
                int c = w*32 + ms*16 + q*4 + r;
                float h = Gs[c]*((acc[ms][ct][r] - mean)*inv) + Bts[c];
                o4[r] = (short)f2bf(gelu_f(h));
            }
            *(s4v*)(outT + rowb + w*32 + ms*16 + q*4) = o4;
        }
    }
}

// ---------------- unified ASPP v5: N=128, dbuf DMA pipeline, counted vmcnt (no drains) ----------------
// y=0..2: dilated 3x3 (d=3,6,9) -> cat slots 1..3 | y=3: a0 1x1 -> slot 0 | y=4: pool -> slot 4
// Stage = (tap,kc) with K=64 (proven pitch-64 rl8/gch swizzle). Double-buffered SB[2] (96 KB);
// issue(s+1) into buf^1 -> wait vmcnt(6) (stage-s's 6 DMAs only; s+1 stays in flight) -> barrier
// -> 32 MFMA/wave -> barrier. Zero vmcnt(0) drains in steady state (k_branch1-proven schedule).
__global__ __launch_bounds__(512, 2)
void k_aspp(const unsigned short* __restrict__ w_a0, const unsigned short* __restrict__ w_d3,
            const unsigned short* __restrict__ w_d6, const unsigned short* __restrict__ w_d9,
            const unsigned short* __restrict__ BT,
            const float* __restrict__ a0_g, const float* __restrict__ a0_b,
            const float* __restrict__ a1_g, const float* __restrict__ a1_b,
            const float* __restrict__ a2_g, const float* __restrict__ a2_b,
            const float* __restrict__ a3_g, const float* __restrict__ a3_b,
            const float* __restrict__ gp, const float* __restrict__ ap_w,
            const float* __restrict__ ap_g, const float* __restrict__ ap_b,
            const float* __restrict__ zbuf,
            unsigned short* __restrict__ catT){
    int br = blockIdx.y, b = blockIdx.z;
    int t = threadIdx.x;
    // per buffer: A 256x64 (16384 shorts) | B 128x64 (8192 shorts) = 48 KB; x2 = 96 KB
    __shared__ __align__(16) unsigned short SB[2][24576];
    __shared__ float Gs[256], Bts[256];
    if (br == 4){
        // ---- pool + broadcast ----
        int p0 = blockIdx.x*128;
        float* z_s = (float*)&SB[0][0];                   // 256 f32
        unsigned short* bp_s = &SB[0][2048];              // 256 bf16
        float* stat = (float*)&SB[0][4096];
        if (t < 256){
            float z = 0.f;
            for (int c = 0; c < 256; c++) z += gp[b*256 + c] * ap_w[t*256 + c];
            z_s[t] = z;
        }
        __syncthreads();
        if (t == 0){
            float s = 0.f, s2 = 0.f;
            for (int c = 0; c < 256; c++){ s += z_s[c]; s2 += z_s[c]*z_s[c]; }
            float mean = s / 256.f, var = s2 / 256.f - mean*mean;
            stat[0] = mean; stat[1] = rsqrtf(var + 1e-6f);
        }
        __syncthreads();
        if (t < 256){
            float h = ap_g[t] * ((z_s[t] - stat[0]) * stat[1]) + ap_b[t];
            bp_s[t] = f2bf(gelu_f(h));
        }
        __syncthreads();
        for (int it = 0; it < 8; it++){
            int i = it*512 + t;
            int pl = i >> 5, cj = (i & 31) * 8;
            s8v v8;
            #pragma unroll
            for (int k2 = 0; k2 < 8; k2++) v8[k2] = (short)bp_s[cj + k2];
            *(s8v*)(catT + ((long long)b*HW + p0 + pl)*1280 + 1024 + cj) = v8;
        }
        return;
    }
    // ---- conv branches: br 0..2 = dilated d=3/6/9 (slots 1..3), br 3 = a0 (slot 0) ----
    int n0 = blockIdx.x * 128;
    const unsigned short* BTb = BT + (long long)b*HW*256;
    const unsigned short* A  = (br==0) ? w_d3 : (br==1) ? w_d6 : (br==2) ? w_d9 : w_a0;
    const float* g   = (br==0) ? a1_g : (br==1) ? a2_g : (br==2) ? a3_g : a0_g;
    const float* bta = (br==0) ? a1_b : (br==1) ? a2_b : (br==2) ? a3_b : a0_b;
    int d    = (br==0) ? 3 : (br==1) ? 6 : (br==2) ? 9 : 0;
    int slot = (br==3) ? 0 : (br+1);
    int NS   = (br==3) ? 4 : 36;                          // (tap,kc) stages, kc fastest
    if (t < 256){ Gs[t] = g[t]; Bts[t] = bta[t]; }

    int w = t>>6, lane = t&63, m = lane&15, q = lane>>4;
    int wr = w>>1, wc = w&1;                              // wave tile: rows wr*64.., cols wc*64..
    int rsw = m&7;                                        // read-side swizzle key
    int rl8 = lane>>3;                                    // lane's row within an 8-row DMA group
    int gch = (lane&7) ^ rl8;                             // pre-swizzled source chunk
    int aoff = rl8*256 + gch*8;                           // per-lane A source offset (shorts)
    int y0 = n0 >> 6;                                     // image row of first tile position

    f4v acc[4][4];
    #pragma unroll
    for (int ms = 0; ms < 4; ms++)
        #pragma unroll
        for (int ct = 0; ct < 4; ct++){ f4v z = {0.f,0.f,0.f,0.f}; acc[ms][ct] = z; }

    auto issue = [&](int s, int buf){                     // 6 DMA/wave: 4 A + 2 B
        int tap = s>>2, kc = s&3;
        int dy = tap/3 - 1, dx = tap - (tap/3)*3 - 1;     // d==0 (a0) kills offsets
        unsigned short* dst = &SB[buf][0];
        const unsigned short* abase = A + tap*65536 + kc*64 + aoff;
        #pragma unroll
        for (int i = 0; i < 4; i++){
            int row0 = w*32 + i*8;
            lds_dma16(abase + row0*256, dst + row0*64);
        }
        int xadd = rl8 + dx*d;
        #pragma unroll
        for (int i = 0; i < 2; i++){
            int bn0 = w*16 + i*8;
            int yy = y0 + (bn0>>6) + dy*d;
            int xs = (bn0 & 63) + xadd;
            const unsigned short* gsrc = ((unsigned)yy < 64u && (unsigned)xs < 64u)
                ? (BTb + (long long)(yy*64 + xs)*256 + kc*64 + gch*8)
                : (const unsigned short*)zbuf;
            lds_dma16(gsrc, dst + 16384 + bn0*64);
        }
    };

    issue(0, 0);
    for (int s = 0; s < NS; ++s){
        int cur = s & 1;
        if (s+1 < NS){
            issue(s+1, cur^1);                            // prefetch next stage into other buffer
            asm volatile("s_waitcnt vmcnt(6)" ::: "memory");  // stage-s's 6 done; s+1 in flight
        } else {
            asm volatile("s_waitcnt vmcnt(0)" ::: "memory");
        }
        __builtin_amdgcn_s_barrier();                     // publish stage s (no drain)
        __builtin_amdgcn_sched_barrier(0);                // rule #18 fence
        const unsigned short* Ac = &SB[cur][0];
        const unsigned short* Bc = &SB[cur][16384];
        #pragma unroll
        for (int ks = 0; ks < 2; ks++){
            s8v bfr[4];
            #pragma unroll
            for (int ct = 0; ct < 4; ct++)
                bfr[ct] = *(const s8v*)&Bc[(wc*64 + ct*16 + m)*64 + ((q + 4*ks) ^ rsw)*8];
            #pragma unroll
            for (int ms = 0; ms < 4; ms++){
                s8v afr = *(const s8v*)&Ac[(wr*64 + ms*16 + m)*64 + ((q + 4*ks) ^ rsw)*8];
                #pragma unroll
                for (int ct = 0; ct < 4; ct++)
                    acc[ms][ct] = __builtin_amdgcn_mfma_f32_16x16x32_bf16(afr, bfr[ct], acc[ms][ct], 0,0,0);
            }
        }
        __builtin_amdgcn_s_barrier();                     // buf[cur] reads done before s+2 overwrites
        __builtin_amdgcn_sched_barrier(0);
    }
    // ---- epilogue: LN over 256 channels per position (128 positions), GELU, store ----
    float* Psum = (float*)&SB[0][0];                      // [4][128]
    float* Psq  = Psum + 512;                             // [4][128]
    float* Mn   = Psq  + 512;                             // [128]
    float* Iv   = Mn   + 128;                             // [128]
    #pragma unroll
    for (int ct = 0; ct < 4; ct++){
        float s = 0.f, s2 = 0.f;
        #pragma unroll
        for (int ms = 0; ms < 4; ms++)
            #pragma unroll
            for (int r = 0; r < 4; r++){ float v = acc[ms][ct][r]; s += v; s2 += v*v; }
        s  += __shfl_xor(s, 16);  s  += __shfl_xor(s, 32);
        s2 += __shfl_xor(s2, 16); s2 += __shfl_xor(s2, 32);
        if (lane < 16){
            Psum[wr*128 + wc*64 + ct*16 + lane] = s;
            Psq [wr*128 + wc*64 + ct*16 + lane] = s2;
        }
    }
    __syncthreads();
    if (t < 128){
        float s  = Psum[t] + Psum[128+t] + Psum[256+t] + Psum[384+t];
        float s2 = Psq [t] + Psq [128+t] + Psq [256+t] + Psq [384+t];
        float mean = s * (1.f/256.f);
        Mn[t] = mean;
        Iv[t] = rsqrtf(s2*(1.f/256.f) - mean*mean + 1e-6f);
    }
    __syncthreads();
    #pragma unroll
    for (int ct = 0; ct < 4; ct++){
        int p = wc*64 + ct*16 + m;
        float mean = Mn[p], inv = Iv[p];
        long long rowb = ((long long)b*HW + n0 + p)*1280 + slot*256;
        #pragma unroll
        for (int ms = 0; ms < 4; ms++){
            s4v o4;
            #pragma unroll
            for (int r = 0; r < 4; r++){
                int c = wr*64 + ms*16 + q*4 + r;
                float h = Gs[c]*((acc[ms][ct][r] - mean)*inv) + Bts[c];
                o4[r] = (short)f2bf(gelu_f(h));
            }
            *(s4v*)(catT + rowb + wr*64 + ms*16 + q*4) = o4;
        }
    }
}

// ---------------- fused 1x1-conv (MFMA) + LN + GELU, 512 thr (proj) — pipelined dbuf DMA ----------------
// A[stage] and B[stage] double-buffered; stage s+1 issued at top of stage s (full-stage prefetch).
// Waits are COUNTED (vmcnt(5)/(4)) — no vmcnt(0) drain in steady state.
__global__ __launch_bounds__(512)
void k_branch1(const unsigned short* __restrict__ A, int K,
               const unsigned short* __restrict__ BT,
               const float* __restrict__ g, const float* __restrict__ beta,
               unsigned short* __restrict__ outT, int outPitch, int colOff){
    int b = blockIdx.y, n0 = blockIdx.x*32;
    const unsigned short* BTb = BT + (long long)b*HW*K;
    __shared__ __align__(16) unsigned short As[2][256*64];  // 64 KB
    __shared__ __align__(16) unsigned short Bs[2][32*64];   // 8 KB
    __shared__ float Psum[8][32], Psq[8][32], Mn[32], Iv[32];
    __shared__ float Gs[256], Bts[256];
    int t = threadIdx.x, w = t>>6, lane = t&63, m = lane&15, q = lane>>4;
    int rl8 = lane>>3, gch = (lane&7) ^ rl8, rsw = m&7;
    if (t < 256){ Gs[t] = g[t]; Bts[t] = beta[t]; }
    f4v acc[2][2];
    #pragma unroll
    for (int ms = 0; ms < 2; ms++)
        #pragma unroll
        for (int ct = 0; ct < 2; ct++){ f4v z = {0.f,0.f,0.f,0.f}; acc[ms][ct] = z; }
    const int NSt = K >> 6;                               // 20 for K=1280
    auto issue = [&](int s, int buf){
        int k0 = s*64;
        #pragma unroll
        for (int i = 0; i < 4; i++){
            int ar = w*32 + i*8;
            lds_dma16(A + (long long)(ar + rl8)*K + k0 + gch*8, &As[buf][ar*64]);
        }
        if (w < 4)
            lds_dma16(BTb + (long long)(n0 + w*8 + rl8)*K + k0 + gch*8, &Bs[buf][w*8*64]);
    };
    issue(0, 0);
    for (int s = 0; s < NSt; ++s){
        int cur = s & 1;
        if (s+1 < NSt){
            issue(s+1, cur^1);                            // prefetch into other buffer
            if (w < 4) asm volatile("s_waitcnt vmcnt(5)" ::: "memory");
            else       asm volatile("s_waitcnt vmcnt(4)" ::: "memory");
        } else {
            asm volatile("s_waitcnt vmcnt(0)" ::: "memory");
        }
        __builtin_amdgcn_s_barrier();                     // publish B(s) (no vmcnt drain)
        __builtin_amdgcn_sched_barrier(0);
        const unsigned short* Ac = &As[cur][0];
        const unsigned short* Bc = &Bs[cur][0];
        #pragma unroll
        for (int ks = 0; ks < 2; ks++){
            s8v bfr[2];
            #pragma unroll
            for (int ct = 0; ct < 2; ct++)
                bfr[ct] = *(const s8v*)&Bc[(ct*16 + m)*64 + ((q + 4*ks) ^ rsw)*8];
            #pragma unroll
            for (int ms = 0; ms < 2; ms++){
                s8v afr = *(const s8v*)&Ac[(w*32 + ms*16 + m)*64 + ((q + 4*ks) ^ rsw)*8];
                #pragma unroll
                for (int ct = 0; ct < 2; ct++)
                    acc[ms][ct] = __builtin_amdgcn_mfma_f32_16x16x32_bf16(afr, bfr[ct], acc[ms][ct], 0,0,0);
            }
        }
        __builtin_amdgcn_s_barrier();                     // buf[cur] reads done before s+2 reuses it
        __builtin_amdgcn_sched_barrier(0);
    }
    __syncthreads();
    ln_epi32(acc, b, n0, w, lane, m, q, t, Gs, Bts, Psum, Psq, Mn, Iv, outT, outPitch, colOff);
}

// ---------------- conv1 (M=128) MFMA, 256 thr, N=32, Kstage=64 — DMA-staged ----------------
__global__ __launch_bounds__(256)
void k_conv1m(const unsigned short* __restrict__ A,      // [128][256] bf16
              const unsigned short* __restrict__ BT,     // [b][HW][256] bf16
              const float* __restrict__ bias,
              unsigned short* __restrict__ outT,         // [b][HW][128] bf16
              unsigned short* __restrict__ outC,         // [b][128][HW] bf16 or null
              float* __restrict__ outF){                 // [b][128][HW] f32 or null
    int b = blockIdx.y, n0 = blockIdx.x*32;
    const unsigned short* BTb = BT + (long long)b*HW*256;
    __shared__ __align__(16) unsigned short As[128*64];  // 16 KB, pitch 64 shorts
    __shared__ __align__(16) unsigned short Bs[32*64];   // 4 KB
    int t = threadIdx.x, w = t>>6, lane = t&63, m = lane&15, q = lane>>4;
    int rl8 = lane>>3, gch = (lane&7) ^ rl8, rsw = m&7;
    f4v acc[2][2];
    #pragma unroll
    for (int ms = 0; ms < 2; ms++)
        #pragma unroll
        for (int ct = 0; ct < 2; ct++){ f4v z = {0.f,0.f,0.f,0.f}; acc[ms][ct] = z; }
    for (int k0 = 0; k0 < 256; k0 += 64){
        // A: 128 rows; wave w stages rows w*32..+31 (4 issues of 8 rows)
        #pragma unroll
        for (int i = 0; i < 4; i++){
            int ar = w*32 + i*8;
            lds_dma16(A + (long long)(ar + rl8)*256 + k0 + gch*8, &As[ar*64]);
        }
        // B: 32 rows; each of the 4 waves stages 8 rows
        lds_dma16(BTb + (long long)(n0 + w*8 + rl8)*256 + k0 + gch*8, &Bs[w*8*64]);
        __syncthreads();                                  // vmcnt(0) drained -> visible
        #pragma unroll
        for (int ks = 0; ks < 2; ks++){
            s8v bfr[2];
            #pragma unroll
            for (int ct = 0; ct < 2; ct++)
                bfr[ct] = *(const s8v*)&Bs[(ct*16 + m)*64 + ((q + 4*ks) ^ rsw)*8];
            #pragma unroll
            for (int ms = 0; ms < 2; ms++){
                s8v afr = *(const s8v*)&As[(w*32 + ms*16 + m)*64 + ((q + 4*ks) ^ rsw)*8];
                #pragma unroll
                for (int ct = 0; ct < 2; ct++)
                    acc[ms][ct] = __builtin_amdgcn_mfma_f32_16x16x32_bf16(afr, bfr[ct], acc[ms][ct], 0,0,0);
            }
        }
        __syncthreads();                                  // reads done before next DMA
    }
    #pragma unroll
    for (int ct = 0; ct < 2; ct++){
        int p = n0 + ct*16 + m;
        #pragma unroll
        for (int ms = 0; ms < 2; ms++){
            s4v o4;
            float vals[4];
            #pragma unroll
            for (int r = 0; r < 4; r++){
                int c = w*32 + ms*16 + q*4 + r;
                vals[r] = acc[ms][ct][r] + bias[c];
                o4[r] = (short)f2bf(vals[r]);
            }
            *(s4v*)(outT + ((long long)b*HW + p)*128 + w*32 + ms*16 + q*4) = o4;
            if (outC){
                #pragma unroll
                for (int r = 0; r < 4; r++){
                    int c = w*32 + ms*16 + q*4 + r;
                    outC[((long long)b*128 + c)*HW + p] = (unsigned short)o4[r];
                }
            }
            if (outF){
                #pragma unroll
                for (int r = 0; r < 4; r++){
                    int c = w*32 + ms*16 + q*4 + r;
                    outF[((long long)b*128 + c)*HW + p] = vals[r];
                }
            }
        }
    }
}

// ---------------- attention pass 1 (split-j, 128 k-rows/block, no-max softmax) ----------------
__global__ __launch_bounds__(256)
void k_attn_stats3(const unsigned short* __restrict__ QT,
                   const unsigned short* __restrict__ PT,
                   float* __restrict__ lpart){
    int b = blockIdx.z, jc = blockIdx.y, k0 = blockIdx.x * 128;
    const unsigned short* QTb = QT + (long long)b * HW * CO;
    const unsigned short* PTb = PT + (long long)b * HW * CO;
    __shared__ unsigned short Ps[2][64][132];
    int t = threadIdx.x;
    int w = t >> 6, lane = t & 63, m = lane & 15, q = lane >> 4;
    s8v a[2][4];
    #pragma unroll
    for (int kh = 0; kh < 2; kh++)
        #pragma unroll
        for (int ks = 0; ks < 4; ks++)
            a[kh][ks] = *(const s8v*)(QTb + (long long)(k0 + kh*64 + w*16 + m) * CO + q*8 + ks*32);
    float rl[2][4];
    #pragma unroll
    for (int kh = 0; kh < 2; kh++)
        #pragma unroll
        for (int r = 0; r < 4; r++) rl[kh][r] = 0.f;
    const float scale = 0.015625f;           // 1/sqrt(4096)
    int jbase = jc * 1024;
    int sr = t >> 2, sch = t & 3;
    uint4 pf[4];
    {   const uint4* src = (const uint4*)(PTb + (long long)(jbase + sr) * CO + sch * 32);
        #pragma unroll
        for (int i = 0; i < 4; i++) pf[i] = src[i];
    }
    for (int jt = 0; jt < 16; jt++){
        int cur = jt & 1;
        {   uint4* dst = (uint4*)&Ps[cur][sr][sch * 32];
            #pragma unroll
            for (int i = 0; i < 4; i++) dst[i] = pf[i];
        }
        __syncthreads();
        if (jt < 15){
            const uint4* src = (const uint4*)(PTb + (long long)(jbase + (jt+1)*64 + sr) * CO + sch * 32);
            #pragma unroll
            for (int i = 0; i < 4; i++) pf[i] = src[i];
        }
        #pragma unroll
        for (int kh = 0; kh < 2; kh++){
            float sv[4][4];
            #pragma unroll
            for (int ct = 0; ct < 4; ct++){
                f4v acc = {0.f,0.f,0.f,0.f};
                #pragma unroll
                for (int ks = 0; ks < 4; ks++){
                    s8v bv = *(const s8v*)&Ps[cur][ct*16 + m][q*8 + ks*32];
                    acc = __builtin_amdgcn_mfma_f32_16x16x32_bf16(a[kh][ks], bv, acc, 0, 0, 0);
                }
                #pragma unroll
                for (int r = 0; r < 4; r++) sv[ct][r] = acc[r] * scale;
            }
            #pragma unroll
            for (int r = 0; r < 4; r++){
                float se = __expf(sv[0][r]) + __expf(sv[1][r])
                         + __expf(sv[2][r]) + __expf(sv[3][r]);
                #pragma unroll
                for (int msk = 1; msk < 16; msk <<= 1) se += __shfl_xor(se, msk);
                rl[kh][r] += se;
            }
        }
    }
    if (m == 0){
        #pragma unroll
        for (int kh = 0; kh < 2; kh++)
            #pragma unroll
            for (int r = 0; r < 4; r++){
                int k = k0 + kh*64 + w*16 + q*4 + r;
                lpart[(long long)jc * (NB*HW) + (long long)b*HW + k] = rl[kh][r];
            }
    }
}

// ---------------- attention pass 2 (split-k x2): wave-private DMA pipeline, counted vmcnt ----------------
__global__ __launch_bounds__(256)
void k_attn_apply2(const unsigned short* __restrict__ QT,
                   const unsigned short* __restrict__ PT,
                   const unsigned short* __restrict__ Pb,
                   const float* __restrict__ lpart,
                   float* __restrict__ Lp){
    int b = blockIdx.z, kc = blockIdx.y, j0 = blockIdx.x * 64;
    const unsigned short* QTb = QT + (long long)b * HW * CO;
    const unsigned short* PTb = PT + (long long)b * HW * CO;
    const unsigned short* Pbb = Pb + (long long)b * CO * HW;
    __shared__ __align__(16) unsigned short Qks[64*128];  // 16 KB
    __shared__ __align__(16) unsigned short Pcs[128*64];  // 16 KB
    __shared__ unsigned short Et[64][72];
    __shared__ float Il[2048];
    int t = threadIdx.x;
    int w = t >> 6, lane = t & 63, m = lane & 15, q = lane >> 4;
    int kbase = kc * 2048;
    int rl4 = lane >> 4;                                  // Qks DMA: row within 4-row group
    int rl8 = lane >> 3;                                  // Pcs DMA: row within 8-row group
    int gch8 = (lane & 7) ^ rl8;                          // Pcs source chunk
    {   // fused stat combine (plain sum, no-max): Il for this block's k-range
        #pragma unroll
        for (int r = 0; r < 8; r++){
            int kl = t*8 + r;
            long long gi = (long long)b*HW + kbase + kl;
            float l = lpart[gi] + lpart[gi+16384] + lpart[gi+32768] + lpart[gi+49152];
            Il[kl] = 1.f / l;
        }
    }
    {   // stage PT j-tile into Qks (4 issues/wave) then Pcs(kt=0) (4 issues/wave)
        #pragma unroll
        for (int i = 0; i < 4; i++){
            int rowb = w*16 + i*4;
            int gch = (lane & 15) ^ ((rowb & 15) + rl4);
            lds_dma16(PTb + (long long)(j0 + rowb + rl4)*CO + gch*8, &Qks[rowb*128]);
        }
        #pragma unroll
        for (int i = 0; i < 4; i++){
            int rowb = w*32 + i*8;
            lds_dma16(Pbb + (long long)(rowb + rl8)*HW + kbase + gch8*8, &Pcs[rowb*64]);
        }
    }
    asm volatile("s_waitcnt vmcnt(4) lgkmcnt(0)" ::: "memory");  // PT done; Il written; Pcs(0) in flight
    __builtin_amdgcn_s_barrier();                                // publish PT + Il
    __builtin_amdgcn_sched_barrier(0);
    s8v bj[4][4];
    #pragma unroll
    for (int ct = 0; ct < 4; ct++)
        #pragma unroll
        for (int ks = 0; ks < 4; ks++)
            bj[ct][ks] = *(const s8v*)&Qks[(ct*16 + m)*128 + ((q + 4*ks) ^ m)*8];
    asm volatile("s_waitcnt lgkmcnt(0)" ::: "memory");           // bj in regs
    __builtin_amdgcn_s_barrier();                                // all waves done reading PT tile
    __builtin_amdgcn_sched_barrier(0);
    {   // Qks <- QT k-tile for kt=0
        #pragma unroll
        for (int i = 0; i < 4; i++){
            int rowb = w*16 + i*4;
            int gch = (lane & 15) ^ ((rowb & 15) + rl4);
            lds_dma16(QTb + (long long)(kbase + rowb + rl4)*CO + gch*8, &Qks[rowb*128]);
        }
    }
    f4v accL[2][4];
    #pragma unroll
    for (int mt = 0; mt < 2; mt++)
        #pragma unroll
        for (int ct = 0; ct < 4; ct++){ f4v z = {0.f,0.f,0.f,0.f}; accL[mt][ct] = z; }
    const float scale = 0.015625f;
    for (int kt = 0; kt < 32; kt++){
        int k0 = kbase + kt*64;
        // wait this wave's Qks(kt) (oldest); Pcs stays in flight (kt=0: queue order differs -> drain)
        if (kt == 0) asm volatile("s_waitcnt vmcnt(0)" ::: "memory");
        else         asm volatile("s_waitcnt vmcnt(4)" ::: "memory");
        __builtin_amdgcn_sched_barrier(0);
        // ---- QK phase (own Qks rows) ----
        s8v aS[4];
        #pragma unroll
        for (int ks = 0; ks < 4; ks++)
            aS[ks] = *(const s8v*)&Qks[(w*16 + m)*128 + ((q + 4*ks) ^ m)*8];
        float il[4];
        #pragma unroll
        for (int r = 0; r < 4; r++) il[r] = Il[kt*64 + w*16 + q*4 + r];
        #pragma unroll
        for (int ct = 0; ct < 4; ct++){
            f4v s = {0.f,0.f,0.f,0.f};
            #pragma unroll
            for (int ks = 0; ks < 4; ks++)
                s = __builtin_amdgcn_mfma_f32_16x16x32_bf16(aS[ks], bj[ct][ks], s, 0, 0, 0);
            s4v e4;
            #pragma unroll
            for (int r = 0; r < 4; r++)
                e4[r] = (short)f2bf(__expf(s[r]*scale) * il[r]);
            *(s4v*)&Et[ct*16 + m][w*16 + q*4] = e4;
        }
        // prefetch own Qks rows for kt+1 (aS consumed via MFMA lgkm waits)
        if (kt+1 < 32){
            #pragma unroll
            for (int i = 0; i < 4; i++){
                int rowb = w*16 + i*4;
                int gch = (lane & 15) ^ ((rowb & 15) + rl4);
                lds_dma16(QTb + (long long)(k0 + 64 + rowb + rl4)*CO + gch*8, &Qks[rowb*128]);
            }
        }
        asm volatile("s_waitcnt lgkmcnt(0)" ::: "memory");   // Et committed
        __builtin_amdgcn_s_barrier();                        // publish Et (DMAs stay in flight)
        __builtin_amdgcn_sched_barrier(0);
        // wait this wave's Pcs(kt) (oldest); Qks(kt+1) stays in flight
        asm volatile("s_waitcnt vmcnt(4)" ::: "memory");
        __builtin_amdgcn_sched_barrier(0);
        // ---- PV phase (own Pcs rows, shared Et) ----
        s8v aP[2][2];
        #pragma unroll
        for (int mt = 0; mt < 2; mt++)
            #pragma unroll
            for (int ks2 = 0; ks2 < 2; ks2++)
                aP[mt][ks2] = *(const s8v*)&Pcs[(w*32 + mt*16 + m)*64 + ((q + 4*ks2) ^ (m&7))*8];
        #pragma unroll
        for (int ct = 0; ct < 4; ct++){
            s8v bE0 = *(const s8v*)&Et[ct*16 + m][q*8];
            s8v bE1 = *(const s8v*)&Et[ct*16 + m][q*8 + 32];
            #pragma unroll
            for (int mt = 0; mt < 2; mt++){
                accL[mt][ct] = __builtin_amdgcn_mfma_f32_16x16x32_bf16(aP[mt][0], bE0, accL[mt][ct], 0, 0, 0);
                accL[mt][ct] = __builtin_amdgcn_mfma_f32_16x16x32_bf16(aP[mt][1], bE1, accL[mt][ct], 0, 0, 0);
            }
        }
        // prefetch own Pcs rows for kt+1 (aP consumed)
        if (kt+1 < 32){
            #pragma unroll
            for (int i = 0; i < 4; i++){
                int rowb = w*32 + i*8;
                lds_dma16(Pbb + (long long)(rowb + rl8)*HW + k0 + 64 + gch8*8, &Pcs[rowb*64]);
            }
        }
        __builtin_amdgcn_s_barrier();                        // Et(kt) reads done before Et(kt+1) writes
        __builtin_amdgcn_sched_barrier(0);
    }
    float* Lpb = Lp + ((long long)(kc*NB + b) * CO) * HW;
    #pragma unroll
    for (int mt = 0; mt < 2; mt++)
        #pragma unroll
        for (int ct = 0; ct < 4; ct++)
            #pragma unroll
            for (int r = 0; r < 4; r++){
                int c = w*32 + mt*16 + q*4 + r;
                Lpb[(long long)c*HW + j0 + ct*16 + m] = accL[mt][ct][r];
            }
}

// ---------------- fused: O = xa + sum(Lp) -> bf16 B-tile -> conv2 -> out f32 (DMA A-staging) ----------------
__global__ __launch_bounds__(256)
void k_outfused(const unsigned short* __restrict__ A,    // w_c2 [256][128] bf16
                const float* __restrict__ Lp, const float* __restrict__ xa,
                const float* __restrict__ bias, float* __restrict__ out){
    int b = blockIdx.y, j0 = blockIdx.x*32;
    __shared__ unsigned short Bs[32][136];
    __shared__ __align__(16) char pool[256*68*2];   // phase1: Bsf[128][33] f32; phase2: As[256*64] bf16
    int t = threadIdx.x;
    // phase 1: O tile f32 = xa + 2 partials (coalesced c-rows)
    {
        float* Bsf = (float*)pool;
        int c = t>>1, jh = t&1;
        long long base = ((long long)b*CO + c)*HW + j0 + jh*16;
        const long long csz = (long long)NB*CO*HW;
        float v[16];
        #pragma unroll
        for (int r = 0; r < 16; r++) v[r] = xa[base + r];
        #pragma unroll
        for (int pidx = 0; pidx < 2; pidx++){
            const float* src = Lp + pidx*csz + base;
            #pragma unroll
            for (int r = 0; r < 16; r++) v[r] += src[r];
        }
        #pragma unroll
        for (int r = 0; r < 16; r++) Bsf[c*33 + jh*16 + r] = v[r];
    }
    __syncthreads();
    // transpose to bf16 B-tile [j][c]
    {
        const float* Bsf = (const float*)pool;
        int j = t>>3, cs = t&7;
        #pragma unroll
        for (int r = 0; r < 16; r++){
            int c = cs*16 + r;
            Bs[j][c] = f2bf(Bsf[c*33 + j]);
        }
    }
    __syncthreads();
    // phase 2: GEMM M=256 x N=32 x K=128, A staged via DMA (pitch 64, swizzled)
    unsigned short* As = (unsigned short*)pool;
    int w = t>>6, lane = t&63, m = lane&15, q = lane>>4;
    int rl8 = lane>>3, gch = (lane&7) ^ rl8, rsw = m&7;
    f4v acc[4][2];
    #pragma unroll
    for (int ms = 0; ms < 4; ms++)
        #pragma unroll
        for (int ct = 0; ct < 2; ct++){ f4v z = {0.f,0.f,0.f,0.f}; acc[ms][ct] = z; }
    for (int k0 = 0; k0 < 128; k0 += 64){
        __syncthreads();                                  // prior reads of pool/As done
        #pragma unroll
        for (int i = 0; i < 8; i++){
            int ar = w*64 + i*8;
            lds_dma16(A + (long long)(ar + rl8)*128 + k0 + gch*8, &As[ar*64]);
        }
        __syncthreads();                                  // vmcnt(0) drained -> visible
        #pragma unroll
        for (int ks = 0; ks < 2; ks++){
            s8v bfr[2];
            #pragma unroll
            for (int ct = 0; ct < 2; ct++) bfr[ct] = *(const s8v*)&Bs[ct*16+m][k0 + ks*32 + q*8];
            #pragma unroll
            for (int ms = 0; ms < 4; ms++){
                s8v afr = *(const s8v*)&As[(w*64 + ms*16 + m)*64 + ((q + 4*ks) ^ rsw)*8];
                #pragma unroll
                for (int ct = 0; ct < 2; ct++)
                    acc[ms][ct] = __builtin_amdgcn_mfma_f32_16x16x32_bf16(afr, bfr[ct], acc[ms][ct], 0,0,0);
            }
        }
    }
    #pragma unroll
    for (int ct = 0; ct < 2; ct++){
        int p = j0 + ct*16 + m;
        #pragma unroll
        for (int ms = 0; ms < 4; ms++)
            #pragma unroll
            for (int r = 0; r < 4; r++){
                int c = w*64 + ms*16 + q*4 + r;
                out[((long long)b*256 + c)*HW + p] = acc[ms][ct][r] + bias[c];
            }
    }
}

extern "C" void kernel_launch(void* const* d_in, const int* in_sizes, int n_in,
                              void* d_out, int out_size, void* d_ws, size_t ws_size,
                              hipStream_t stream) {
    const float* x       = (const float*)d_in[0];
    const float* conv1_w = (const float*)d_in[1];
    const float* conv1_b = (const float*)d_in[2];
    const float* conv2_w = (const float*)d_in[3];
    const float* conv2_b = (const float*)d_in[4];
    const float* cw_w1   = (const float*)d_in[5];
    const float* cw_b1   = (const float*)d_in[6];
    const float* cw_g    = (const float*)d_in[7];
    const float* cw_bt   = (const float*)d_in[8];
    const float* cw_w2   = (const float*)d_in[9];
    const float* cw_b2   = (const float*)d_in[10];
    const float* a0_w    = (const float*)d_in[11];
    const float* a0_g    = (const float*)d_in[12];
    const float* a0_b    = (const float*)d_in[13];
    const float* a1_w    = (const float*)d_in[14];
    const float* a1_g    = (const float*)d_in[15];
    const float* a1_b    = (const float*)d_in[16];
    const float* a2_w    = (const float*)d_in[17];
    const float* a2_g    = (const float*)d_in[18];
    const float* a2_b    = (const float*)d_in[19];
    const float* a3_w    = (const float*)d_in[20];
    const float* a3_g    = (const float*)d_in[21];
    const float* a3_b    = (const float*)d_in[22];
    const float* ap_w    = (const float*)d_in[23];
    const float* ap_g    = (const float*)d_in[24];
    const float* ap_b    = (const float*)d_in[25];
    const float* pj_w    = (const float*)d_in[26];
    const float* pj_g    = (const float*)d_in[27];
    const float* pj_b    = (const float*)d_in[28];
    float* out = (float*)d_out;

    // ---- workspace layout ----
    float* ws    = (float*)d_ws;
    float* avg   = ws;                  // 1024
    float* mx    = ws + 1024;           // 1024
    float* sv    = ws + 2048;           // 1024
    float* gp    = ws + 3072;           // 1024
    float* zbuf  = ws + 4096;           // 256 f32 zero-page for OOB DMA
    float* xa    = ws + 37888;          // 2,097,152
    float* lpart = xa + 2097152;        // 65536
    unsigned short* sb = (unsigned short*)(ws + 4232192);
    unsigned short* xT    = sb;                    // 4,194,304
    unsigned short* xcT   = sb + 4194304;          // 4,194,304
    unsigned short* catT  = sb + 8388608;          // 20,971,520
    unsigned short* projT = sb + 29360128;         // 4,194,304
    unsigned short* P_bf  = sb + 33554432;         // 2,097,152
    unsigned short* PT_bf = sb + 35651584;         // 2,097,152
    unsigned short* QT_bf = sb + 37748736;         // 2,097,152
    unsigned short* w_c1  = sb + 41943040;         // 32768
    unsigned short* w_a0  = sb + 41975808;         // 65536
    unsigned short* w_pj  = sb + 42041344;         // 327680
    unsigned short* w_c2  = sb + 42369024;         // 32768
    unsigned short* w_d3  = sb + 42401792;         // 589824
    unsigned short* w_d6  = sb + 42991616;         // 589824
    unsigned short* w_d9  = sb + 43581440;         // 589824
    float* Lp = (float*)catT;           // alias: catT dead after proj (16.8MB in 42MB region)

    // ---- rowstats + all weight casts (one launch) ----
    k_pre<<<dim3(9728), 256, 0, stream>>>(x, avg, mx,
                                          conv1_w, a0_w, pj_w, conv2_w, a1_w, a2_w, a3_w,
                                          w_c1, w_a0, w_pj, w_c2, w_d3, w_d6, w_d9);
    k_cw<<<dim3(NB), 256, 0, stream>>>(avg, mx, cw_w1, cw_b1, cw_g, cw_bt, cw_w2, cw_b2, sv, gp, zbuf);

    // ---- x -> xT bf16 and xcT ----
    k_xT<<<dim3(64, 4, NB), 256, 0, stream>>>(x, sv, xT, xcT);

    // ---- x1 = conv1(x)+b -> P_bf/PT_bf ----
    k_conv1m<<<dim3(128, NB), 256, 0, stream>>>(w_c1, xT, conv1_b, PT_bf, P_bf, nullptr);

    // ---- ASPP: 3 dilated convs + a0 + pool/bcast in ONE launch (N=128, dbuf counted-vmcnt) ----
    k_aspp<<<dim3(32, 5, NB), 512, 0, stream>>>(w_a0, w_d3, w_d6, w_d9, xcT,
                                                a0_g, a0_b, a1_g, a1_b, a2_g, a2_b, a3_g, a3_b,
                                                gp, ap_w, ap_g, ap_b, zbuf, catT);

    // ---- proj = GELU(LN(conv1x1(cat))) -> projT bf16 (pipelined dbuf DMA) ----
    k_branch1<<<dim3(128, NB), 512, 0, stream>>>(w_pj, 1280, catT, pj_g, pj_b, projT, 256, 0);

    // ---- xa = conv1(proj)+b -> xa f32 + QT_bf ----
    k_conv1m<<<dim3(128, NB), 256, 0, stream>>>(w_c1, projT, conv1_b, QT_bf, nullptr, xa);

    // ---- attention (no-max softmax; comb fused into apply; kc-split = 2; counted-vmcnt apply) ----
    k_attn_stats3<<<dim3(32, 4, NB), 256, 0, stream>>>(QT_bf, PT_bf, lpart);
    k_attn_apply2<<<dim3(64, 2, NB), 256, 0, stream>>>(QT_bf, PT_bf, P_bf, lpart, Lp);

    // ---- out = conv2(xa + sum Lp) + b (fused) ----
    k_outfused<<<dim3(128, NB), 256, 0, stream>>>(w_c2, Lp, xa, conv2_b, out);

    (void)in_sizes; (void)n_in; (void)out_size; (void)ws_size;
}

// Round 8
// 384.283 us; speedup vs baseline: 1.0311x; 1.0311x over previous
//
#include <hip/hip_runtime.h>
#include <hip/hip_bf16.h>
#include <math.h>

// Problem constants (B=4, Cin=256, Cout=128, H=W=64)
#define NB 4
#define CI 256
#define CO 128
#define HW 4096

typedef __attribute__((ext_vector_type(8))) short s8v;   // 8 bf16 = 4 VGPRs (MFMA A/B frag)
typedef __attribute__((ext_vector_type(4))) short s4v;
typedef __attribute__((ext_vector_type(4))) float f4v;   // MFMA C/D frag

__device__ __forceinline__ unsigned short f2bf(float f){
    __hip_bfloat16 h = __float2bfloat16(f);   // RNE
    return *reinterpret_cast<unsigned short*>(&h);
}

// async global->LDS DMA, 16B per lane; LDS dest = wave-uniform base + lane*16
__device__ __forceinline__ void lds_dma16(const void* g, void* l){
    __builtin_amdgcn_global_load_lds((const __attribute__((address_space(1))) unsigned int*)g,
                                     (__attribute__((address_space(3))) unsigned int*)l,
                                     16, 0, 0);
}

// A&S 7.1.26 erf (max abs err 1.5e-7)
__device__ __forceinline__ float gelu_f(float x){
    float z  = x * 0.70710678118654752f;
    float az = fabsf(z);
    float tt = 1.f / (1.f + 0.3275911f * az);
    float poly = tt*(0.254829592f + tt*(-0.284496736f + tt*(1.421413741f +
                 tt*(-1.453152027f + tt*1.061405429f))));
    float erfv = 1.f - poly * __expf(-az*az);
    erfv = (z < 0.f) ? -erfv : erfv;
    return 0.5f * x * (1.f + erfv);
}

// ---------------- fused: per-channel avg/max (blocks 0..1023) + ALL weight casts ----------------
__global__ void k_pre(const float* __restrict__ x, float* __restrict__ avg, float* __restrict__ mx,
                      const float* __restrict__ c1, const float* __restrict__ a0,
                      const float* __restrict__ pj, const float* __restrict__ c2,
                      const float* __restrict__ d3, const float* __restrict__ d6,
                      const float* __restrict__ d9,
                      unsigned short* __restrict__ w_c1, unsigned short* __restrict__ w_a0,
                      unsigned short* __restrict__ w_pj, unsigned short* __restrict__ w_c2,
                      unsigned short* __restrict__ w_d3, unsigned short* __restrict__ w_d6,
                      unsigned short* __restrict__ w_d9){
    int blk = blockIdx.x;
    int t = threadIdx.x;
    if (blk < 1024){
        const float* p = x + (long long)blk * HW;
        float s = 0.f, m = -1e30f;
        for (int i = t; i < HW; i += 256){ float v = p[i]; s += v; m = fmaxf(m, v); }
        __shared__ float ss[256], sm[256];
        ss[t] = s; sm[t] = m; __syncthreads();
        for (int o = 128; o > 0; o >>= 1){
            if (t < o){ ss[t] += ss[t+o]; sm[t] = fmaxf(sm[t], sm[t+o]); }
            __syncthreads();
        }
        if (t == 0){ avg[blk] = ss[0] / (float)HW; mx[blk] = sm[0]; }
        return;
    }
    int i = (blk - 1024)*256 + t;
    if (i < 458752){
        if (i < 32768)        w_c1[i]        = f2bf(c1[i]);
        else if (i < 98304)   w_a0[i-32768]  = f2bf(a0[i-32768]);
        else if (i < 425984)  w_pj[i-98304]  = f2bf(pj[i-98304]);
        else                  w_c2[i-425984] = f2bf(c2[i-425984]);
    } else {
        int j = i - 458752;
        int which = j / 589824;
        int l = j - which*589824;
        int tap = l >> 16, rem = l & 65535, o = rem >> 8, ci = rem & 255;
        const float* src = (which==0) ? d3 : ((which==1) ? d6 : d9);
        unsigned short* dst = (which==0) ? w_d3 : ((which==1) ? w_d6 : w_d9);
        dst[l] = f2bf(src[o*2304 + ci*9 + tap]);
    }
}

// ---------------- ChannelWeighting; also gp = avg*(1+s); block 0 zeroes the DMA zero-page ----------------
__global__ void k_cw(const float* __restrict__ avg, const float* __restrict__ mx,
                     const float* __restrict__ w1, const float* __restrict__ b1,
                     const float* __restrict__ lng, const float* __restrict__ lnb,
                     const float* __restrict__ w2, const float* __restrict__ b2,
                     float* __restrict__ sv, float* __restrict__ gp,
                     float* __restrict__ zb){
    int b = blockIdx.x, t = threadIdx.x;
    if (b == 0) zb[t] = 0.f;                 // 1 KB zero-page for OOB DMA lanes
    __shared__ float o_s[256];
    __shared__ float h_s[128];
    __shared__ float stat[2];
    float a = avg[b*256 + t];
    o_s[t] = fabsf(a - mx[b*256 + t]) * a;
    __syncthreads();
    if (t < 128){
        float h = b1[t];
        for (int i = 0; i < 256; i++) h += o_s[i] * w1[t*256 + i];
        h_s[t] = h;
    }
    __syncthreads();
    if (t == 0){
        float s = 0.f, s2 = 0.f;
        for (int j = 0; j < 128; j++){ s += h_s[j]; s2 += h_s[j]*h_s[j]; }
        float mean = s / 128.f;
        float var  = s2 / 128.f - mean*mean;
        stat[0] = mean; stat[1] = rsqrtf(var + 1e-5f);
    }
    __syncthreads();
    if (t < 128) h_s[t] = lng[t] * ((h_s[t] - stat[0]) * stat[1]) + lnb[t];
    __syncthreads();
    float z = b2[t];
    for (int j = 0; j < 128; j++) z += h_s[j] * w2[t*128 + j];
    float sig = 1.f / (1.f + __expf(-z));
    sv[b*256 + t] = sig;
    gp[b*256 + t] = a * (1.f + sig);
}

// ---------------- x -> xT bf16 [b][HW][256] and xcT = bf16(x*(1+s)) ----------------
__global__ void k_xT(const float* __restrict__ x, const float* __restrict__ sv,
                     unsigned short* __restrict__ xT, unsigned short* __restrict__ xcT){
    int b = blockIdx.z, c0 = blockIdx.y*64, h0 = blockIdx.x*64;
    __shared__ unsigned short T1[64][66], T2[64][66];
    int t = threadIdx.x;
    int hl = t & 63, cs = t >> 6;
    #pragma unroll
    for (int r = 0; r < 16; r++){
        int c = cs*16 + r;
        float v = x[((long long)b*256 + c0 + c)*HW + h0 + hl];
        float sc = 1.f + sv[b*256 + c0 + c];
        T1[c][hl] = f2bf(v);
        T2[c][hl] = f2bf(v*sc);
    }
    __syncthreads();
    int cl = t & 63, hs = t >> 6;
    #pragma unroll
    for (int r = 0; r < 16; r++){
        int h = hs*16 + r;
        long long o = ((long long)b*HW + h0 + h)*256 + c0 + cl;
        xT[o]  = T1[cl][h];
        xcT[o] = T2[cl][h];
    }
}

// ============ 8-wave epilogue, N=32: LN(256ch)+GELU -> transposed bf16 ============
__device__ __forceinline__ void ln_epi32(f4v acc[2][2],
        int b, int n0, int w, int lane, int m, int q, int t,
        const float* Gs, const float* Bts,
        float (*Psum)[32], float (*Psq)[32], float* Mn, float* Iv,
        unsigned short* __restrict__ outT, int outPitch, int colOff){
    float ls[2], ls2[2];
    #pragma unroll
    for (int ct = 0; ct < 2; ct++){
        float s = 0.f, s2 = 0.f;
        #pragma unroll
        for (int ms = 0; ms < 2; ms++)
            #pragma unroll
            for (int r = 0; r < 4; r++){ float v = acc[ms][ct][r]; s += v; s2 += v*v; }
        ls[ct] = s; ls2[ct] = s2;
    }
    #pragma unroll
    for (int ct = 0; ct < 2; ct++){
        ls[ct]  += __shfl_xor(ls[ct], 16);  ls[ct]  += __shfl_xor(ls[ct], 32);
        ls2[ct] += __shfl_xor(ls2[ct], 16); ls2[ct] += __shfl_xor(ls2[ct], 32);
    }
    if (lane < 16){
        #pragma unroll
        for (int ct = 0; ct < 2; ct++){ Psum[w][ct*16+lane] = ls[ct]; Psq[w][ct*16+lane] = ls2[ct]; }
    }
    __syncthreads();
    if (t < 32){
        float s = 0.f, s2 = 0.f;
        #pragma unroll
        for (int ww = 0; ww < 8; ww++){ s += Psum[ww][t]; s2 += Psq[ww][t]; }
        float mean = s * (1.f/256.f);
        Mn[t] = mean;
        Iv[t] = rsqrtf(s2*(1.f/256.f) - mean*mean + 1e-6f);
    }
    __syncthreads();
    #pragma unroll
    for (int ct = 0; ct < 2; ct++){
        int p = ct*16 + m;
        float mean = Mn[p], inv = Iv[p];
        long long rowb = ((long long)b*HW + n0 + p)*outPitch + colOff;
        #pragma unroll
        for (int ms = 0; ms < 2; ms++){
            s4v o4;
            #pragma unroll
            for (int r = 0; r < 4; r++){
                int c = w*32 + ms*16 + q*4 + r;
                float h = Gs[c]*((acc[ms][ct][r] - mean)*inv) + Bts[c];
                o4[r] = (short)f2bf(gelu_f(h));
            }
            *(s4v*)(outT + rowb + w*32 + ms*16 + q*4) = o4;
        }
    }
}

// ---------------- unified ASPP v6: N=256 tile, dbuf DMA pipeline, counted vmcnt ----------------
// y=0..2: dilated 3x3 (d=3,6,9) -> cat slots 1..3 | y=3: a0 1x1 -> slot 0 | y=4: pool -> slot 4
// Grid x=16 -> 256 heavy blocks = exactly 1/CU (perfect balance). 8 waves as 2M x 4N,
// wave tile 128x64, acc[8][4]=128 VGPR. Stage = (tap,kc), K=64, proven pitch-64 rl8/gch swizzle.
// Dbuf SB[2][32768] (128 KB); issue(s+1) -> vmcnt(8) -> barrier -> 64 MFMA/wave -> barrier.
__global__ __launch_bounds__(512, 2)
void k_aspp(const unsigned short* __restrict__ w_a0, const unsigned short* __restrict__ w_d3,
            const unsigned short* __restrict__ w_d6, const unsigned short* __restrict__ w_d9,
            const unsigned short* __restrict__ BT,
            const float* __restrict__ a0_g, const float* __restrict__ a0_b,
            const float* __restrict__ a1_g, const float* __restrict__ a1_b,
            const float* __restrict__ a2_g, const float* __restrict__ a2_b,
            const float* __restrict__ a3_g, const float* __restrict__ a3_b,
            const float* __restrict__ gp, const float* __restrict__ ap_w,
            const float* __restrict__ ap_g, const float* __restrict__ ap_b,
            const float* __restrict__ zbuf,
            unsigned short* __restrict__ catT){
    int br = blockIdx.y, b = blockIdx.z;
    int t = threadIdx.x;
    // per buffer: A 256x64 (16384 shorts) | B 256x64 (16384 shorts) = 64 KB; x2 = 128 KB
    __shared__ __align__(16) unsigned short SB[2][32768];
    __shared__ float Gs[256], Bts[256];
    if (br == 4){
        // ---- pool + broadcast (256 positions per block) ----
        int p0 = blockIdx.x*256;
        float* z_s = (float*)&SB[0][0];                   // 256 f32
        unsigned short* bp_s = &SB[0][2048];              // 256 bf16
        float* stat = (float*)&SB[0][4096];
        if (t < 256){
            float z = 0.f;
            for (int c = 0; c < 256; c++) z += gp[b*256 + c] * ap_w[t*256 + c];
            z_s[t] = z;
        }
        __syncthreads();
        if (t == 0){
            float s = 0.f, s2 = 0.f;
            for (int c = 0; c < 256; c++){ s += z_s[c]; s2 += z_s[c]*z_s[c]; }
            float mean = s / 256.f, var = s2 / 256.f - mean*mean;
            stat[0] = mean; stat[1] = rsqrtf(var + 1e-6f);
        }
        __syncthreads();
        if (t < 256){
            float h = ap_g[t] * ((z_s[t] - stat[0]) * stat[1]) + ap_b[t];
            bp_s[t] = f2bf(gelu_f(h));
        }
        __syncthreads();
        for (int it = 0; it < 16; it++){
            int i = it*512 + t;
            int pl = i >> 5, cj = (i & 31) * 8;
            s8v v8;
            #pragma unroll
            for (int k2 = 0; k2 < 8; k2++) v8[k2] = (short)bp_s[cj + k2];
            *(s8v*)(catT + ((long long)b*HW + p0 + pl)*1280 + 1024 + cj) = v8;
        }
        return;
    }
    // ---- conv branches: br 0..2 = dilated d=3/6/9 (slots 1..3), br 3 = a0 (slot 0) ----
    int n0 = blockIdx.x * 256;
    const unsigned short* BTb = BT + (long long)b*HW*256;
    const unsigned short* A  = (br==0) ? w_d3 : (br==1) ? w_d6 : (br==2) ? w_d9 : w_a0;
    const float* g   = (br==0) ? a1_g : (br==1) ? a2_g : (br==2) ? a3_g : a0_g;
    const float* bta = (br==0) ? a1_b : (br==1) ? a2_b : (br==2) ? a3_b : a0_b;
    int d    = (br==0) ? 3 : (br==1) ? 6 : (br==2) ? 9 : 0;
    int slot = (br==3) ? 0 : (br+1);
    int NS   = (br==3) ? 4 : 36;                          // (tap,kc) stages, kc fastest
    if (t < 256){ Gs[t] = g[t]; Bts[t] = bta[t]; }

    int w = t>>6, lane = t&63, m = lane&15, q = lane>>4;
    int wr = w>>2, wc = w&3;                              // wave tile: rows wr*128.., cols wc*64..
    int rsw = m&7;                                        // read-side swizzle key
    int rl8 = lane>>3;                                    // lane's row within an 8-row DMA group
    int gch = (lane&7) ^ rl8;                             // pre-swizzled source chunk
    int aoff = rl8*256 + gch*8;                           // per-lane A source offset (shorts)
    int y0 = n0 >> 6;                                     // image row of first tile position

    f4v acc[8][4];
    #pragma unroll
    for (int ms = 0; ms < 8; ms++)
        #pragma unroll
        for (int ct = 0; ct < 4; ct++){ f4v z = {0.f,0.f,0.f,0.f}; acc[ms][ct] = z; }

    auto issue = [&](int s, int buf){                     // 8 DMA/wave: 4 A + 4 B
        int tap = s>>2, kc = s&3;
        int dy = tap/3 - 1, dx = tap - (tap/3)*3 - 1;     // d==0 (a0) kills offsets
        unsigned short* dst = &SB[buf][0];
        const unsigned short* abase = A + tap*65536 + kc*64 + aoff;
        #pragma unroll
        for (int i = 0; i < 4; i++){
            int row0 = w*32 + i*8;
            lds_dma16(abase + row0*256, dst + row0*64);
        }
        int xadd = rl8 + dx*d;
        #pragma unroll
        for (int i = 0; i < 4; i++){
            int bn0 = w*32 + i*8;                         // 8-row group lies in ONE image row
            int yy = y0 + (bn0>>6) + dy*d;
            int xs = (bn0 & 63) + xadd;
            const unsigned short* gsrc = ((unsigned)yy < 64u && (unsigned)xs < 64u)
                ? (BTb + (long long)(yy*64 + xs)*256 + kc*64 + gch*8)
                : (const unsigned short*)zbuf;
            lds_dma16(gsrc, dst + 16384 + bn0*64);
        }
    };

    issue(0, 0);
    for (int s = 0; s < NS; ++s){
        int cur = s & 1;
        if (s+1 < NS){
            issue(s+1, cur^1);                            // prefetch next stage into other buffer
            asm volatile("s_waitcnt vmcnt(8)" ::: "memory");  // stage-s's 8 done; s+1 in flight
        } else {
            asm volatile("s_waitcnt vmcnt(0)" ::: "memory");
        }
        __builtin_amdgcn_s_barrier();                     // publish stage s (no drain)
        __builtin_amdgcn_sched_barrier(0);                // rule #18 fence
        const unsigned short* Ac = &SB[cur][0];
        const unsigned short* Bc = &SB[cur][16384];
        #pragma unroll
        for (int ks = 0; ks < 2; ks++){
            s8v bfr[4];
            #pragma unroll
            for (int ct = 0; ct < 4; ct++)
                bfr[ct] = *(const s8v*)&Bc[(wc*64 + ct*16 + m)*64 + ((q + 4*ks) ^ rsw)*8];
            #pragma unroll
            for (int ms = 0; ms < 8; ms++){
                s8v afr = *(const s8v*)&Ac[(wr*128 + ms*16 + m)*64 + ((q + 4*ks) ^ rsw)*8];
                #pragma unroll
                for (int ct = 0; ct < 4; ct++)
                    acc[ms][ct] = __builtin_amdgcn_mfma_f32_16x16x32_bf16(afr, bfr[ct], acc[ms][ct], 0,0,0);
            }
        }
        __builtin_amdgcn_s_barrier();                     // buf[cur] reads done before s+2 overwrites
        __builtin_amdgcn_sched_barrier(0);
    }
    // ---- epilogue: LN over 256 channels per position (256 positions), GELU, store ----
    float* Psum = (float*)&SB[0][0];                      // [2][256]
    float* Psq  = Psum + 512;                             // [2][256]
    float* Mn   = Psq  + 512;                             // [256]
    float* Iv   = Mn   + 256;                             // [256]
    #pragma unroll
    for (int ct = 0; ct < 4; ct++){
        float s = 0.f, s2 = 0.f;
        #pragma unroll
        for (int ms = 0; ms < 8; ms++)
            #pragma unroll
            for (int r = 0; r < 4; r++){ float v = acc[ms][ct][r]; s += v; s2 += v*v; }
        s  += __shfl_xor(s, 16);  s  += __shfl_xor(s, 32);
        s2 += __shfl_xor(s2, 16); s2 += __shfl_xor(s2, 32);
        if (lane < 16){
            Psum[wr*256 + wc*64 + ct*16 + lane] = s;
            Psq [wr*256 + wc*64 + ct*16 + lane] = s2;
        }
    }
    __syncthreads();
    if (t < 256){
        float s  = Psum[t] + Psum[256+t];
        float s2 = Psq [t] + Psq [256+t];
        float mean = s * (1.f/256.f);
        Mn[t] = mean;
        Iv[t] = rsqrtf(s2*(1.f/256.f) - mean*mean + 1e-6f);
    }
    __syncthreads();
    #pragma unroll
    for (int ct = 0; ct < 4; ct++){
        int p = wc*64 + ct*16 + m;
        float mean = Mn[p], inv = Iv[p];
        long long rowb = ((long long)b*HW + n0 + p)*1280 + slot*256;
        #pragma unroll
        for (int ms = 0; ms < 8; ms++){
            s4v o4;
            #pragma unroll
            for (int r = 0; r < 4; r++){
                int c = wr*128 + ms*16 + q*4 + r;
                float h = Gs[c]*((acc[ms][ct][r] - mean)*inv) + Bts[c];
                o4[r] = (short)f2bf(gelu_f(h));
            }
            *(s4v*)(catT + rowb + wr*128 + ms*16 + q*4) = o4;
        }
    }
}

// ---------------- fused 1x1-conv (MFMA) + LN + GELU, 512 thr (proj) — pipelined dbuf DMA ----------------
__global__ __launch_bounds__(512)
void k_branch1(const unsigned short* __restrict__ A, int K,
               const unsigned short* __restrict__ BT,
               const float* __restrict__ g, const float* __restrict__ beta,
               unsigned short* __restrict__ outT, int outPitch, int colOff){
    int b = blockIdx.y, n0 = blockIdx.x*32;
    const unsigned short* BTb = BT + (long long)b*HW*K;
    __shared__ __align__(16) unsigned short As[2][256*64];  // 64 KB
    __shared__ __align__(16) unsigned short Bs[2][32*64];   // 8 KB
    __shared__ float Psum[8][32], Psq[8][32], Mn[32], Iv[32];
    __shared__ float Gs[256], Bts[256];
    int t = threadIdx.x, w = t>>6, lane = t&63, m = lane&15, q = lane>>4;
    int rl8 = lane>>3, gch = (lane&7) ^ rl8, rsw = m&7;
    if (t < 256){ Gs[t] = g[t]; Bts[t] = beta[t]; }
    f4v acc[2][2];
    #pragma unroll
    for (int ms = 0; ms < 2; ms++)
        #pragma unroll
        for (int ct = 0; ct < 2; ct++){ f4v z = {0.f,0.f,0.f,0.f}; acc[ms][ct] = z; }
    const int NSt = K >> 6;                               // 20 for K=1280
    auto issue = [&](int s, int buf){
        int k0 = s*64;
        #pragma unroll
        for (int i = 0; i < 4; i++){
            int ar = w*32 + i*8;
            lds_dma16(A + (long long)(ar + rl8)*K + k0 + gch*8, &As[buf][ar*64]);
        }
        if (w < 4)
            lds_dma16(BTb + (long long)(n0 + w*8 + rl8)*K + k0 + gch*8, &Bs[buf][w*8*64]);
    };
    issue(0, 0);
    for (int s = 0; s < NSt; ++s){
        int cur = s & 1;
        if (s+1 < NSt){
            issue(s+1, cur^1);                            // prefetch into other buffer
            if (w < 4) asm volatile("s_waitcnt vmcnt(5)" ::: "memory");
            else       asm volatile("s_waitcnt vmcnt(4)" ::: "memory");
        } else {
            asm volatile("s_waitcnt vmcnt(0)" ::: "memory");
        }
        __builtin_amdgcn_s_barrier();                     // publish B(s) (no vmcnt drain)
        __builtin_amdgcn_sched_barrier(0);
        const unsigned short* Ac = &As[cur][0];
        const unsigned short* Bc = &Bs[cur][0];
        #pragma unroll
        for (int ks = 0; ks < 2; ks++){
            s8v bfr[2];
            #pragma unroll
            for (int ct = 0; ct < 2; ct++)
                bfr[ct] = *(const s8v*)&Bc[(ct*16 + m)*64 + ((q + 4*ks) ^ rsw)*8];
            #pragma unroll
            for (int ms = 0; ms < 2; ms++){
                s8v afr = *(const s8v*)&Ac[(w*32 + ms*16 + m)*64 + ((q + 4*ks) ^ rsw)*8];
                #pragma unroll
                for (int ct = 0; ct < 2; ct++)
                    acc[ms][ct] = __builtin_amdgcn_mfma_f32_16x16x32_bf16(afr, bfr[ct], acc[ms][ct], 0,0,0);
            }
        }
        __builtin_amdgcn_s_barrier();                     // buf[cur] reads done before s+2 reuses it
        __builtin_amdgcn_sched_barrier(0);
    }
    __syncthreads();
    ln_epi32(acc, b, n0, w, lane, m, q, t, Gs, Bts, Psum, Psq, Mn, Iv, outT, outPitch, colOff);
}

// ---------------- conv1 (M=128) MFMA, 256 thr, N=32, Kstage=64 — DMA-staged ----------------
__global__ __launch_bounds__(256)
void k_conv1m(const unsigned short* __restrict__ A,      // [128][256] bf16
              const unsigned short* __restrict__ BT,     // [b][HW][256] bf16
              const float* __restrict__ bias,
              unsigned short* __restrict__ outT,         // [b][HW][128] bf16
              unsigned short* __restrict__ outC,         // [b][128][HW] bf16 or null
              float* __restrict__ outF){                 // [b][128][HW] f32 or null
    int b = blockIdx.y, n0 = blockIdx.x*32;
    const unsigned short* BTb = BT + (long long)b*HW*256;
    __shared__ __align__(16) unsigned short As[128*64];  // 16 KB, pitch 64 shorts
    __shared__ __align__(16) unsigned short Bs[32*64];   // 4 KB
    int t = threadIdx.x, w = t>>6, lane = t&63, m = lane&15, q = lane>>4;
    int rl8 = lane>>3, gch = (lane&7) ^ rl8, rsw = m&7;
    f4v acc[2][2];
    #pragma unroll
    for (int ms = 0; ms < 2; ms++)
        #pragma unroll
        for (int ct = 0; ct < 2; ct++){ f4v z = {0.f,0.f,0.f,0.f}; acc[ms][ct] = z; }
    for (int k0 = 0; k0 < 256; k0 += 64){
        // A: 128 rows; wave w stages rows w*32..+31 (4 issues of 8 rows)
        #pragma unroll
        for (int i = 0; i < 4; i++){
            int ar = w*32 + i*8;
            lds_dma16(A + (long long)(ar + rl8)*256 + k0 + gch*8, &As[ar*64]);
        }
        // B: 32 rows; each of the 4 waves stages 8 rows
        lds_dma16(BTb + (long long)(n0 + w*8 + rl8)*256 + k0 + gch*8, &Bs[w*8*64]);
        __syncthreads();                                  // vmcnt(0) drained -> visible
        #pragma unroll
        for (int ks = 0; ks < 2; ks++){
            s8v bfr[2];
            #pragma unroll
            for (int ct = 0; ct < 2; ct++)
                bfr[ct] = *(const s8v*)&Bs[(ct*16 + m)*64 + ((q + 4*ks) ^ rsw)*8];
            #pragma unroll
            for (int ms = 0; ms < 2; ms++){
                s8v afr = *(const s8v*)&As[(w*32 + ms*16 + m)*64 + ((q + 4*ks) ^ rsw)*8];
                #pragma unroll
                for (int ct = 0; ct < 2; ct++)
                    acc[ms][ct] = __builtin_amdgcn_mfma_f32_16x16x32_bf16(afr, bfr[ct], acc[ms][ct], 0,0,0);
            }
        }
        __syncthreads();                                  // reads done before next DMA
    }
    #pragma unroll
    for (int ct = 0; ct < 2; ct++){
        int p = n0 + ct*16 + m;
        #pragma unroll
        for (int ms = 0; ms < 2; ms++){
            s4v o4;
            float vals[4];
            #pragma unroll
            for (int r = 0; r < 4; r++){
                int c = w*32 + ms*16 + q*4 + r;
                vals[r] = acc[ms][ct][r] + bias[c];
                o4[r] = (short)f2bf(vals[r]);
            }
            *(s4v*)(outT + ((long long)b*HW + p)*128 + w*32 + ms*16 + q*4) = o4;
            if (outC){
                #pragma unroll
                for (int r = 0; r < 4; r++){
                    int c = w*32 + ms*16 + q*4 + r;
                    outC[((long long)b*128 + c)*HW + p] = (unsigned short)o4[r];
                }
            }
            if (outF){
                #pragma unroll
                for (int r = 0; r < 4; r++){
                    int c = w*32 + ms*16 + q*4 + r;
                    outF[((long long)b*128 + c)*HW + p] = vals[r];
                }
            }
        }
    }
}

// ---------------- attention pass 1 (split-j, 128 k-rows/block, no-max softmax) ----------------
__global__ __launch_bounds__(256)
void k_attn_stats3(const unsigned short* __restrict__ QT,
                   const unsigned short* __restrict__ PT,
                   float* __restrict__ lpart){
    int b = blockIdx.z, jc = blockIdx.y, k0 = blockIdx.x * 128;
    const unsigned short* QTb = QT + (long long)b * HW * CO;
    const unsigned short* PTb = PT + (long long)b * HW * CO;
    __shared__ unsigned short Ps[2][64][132];
    int t = threadIdx.x;
    int w = t >> 6, lane = t & 63, m = lane & 15, q = lane >> 4;
    s8v a[2][4];
    #pragma unroll
    for (int kh = 0; kh < 2; kh++)
        #pragma unroll
        for (int ks = 0; ks < 4; ks++)
            a[kh][ks] = *(const s8v*)(QTb + (long long)(k0 + kh*64 + w*16 + m) * CO + q*8 + ks*32);
    float rl[2][4];
    #pragma unroll
    for (int kh = 0; kh < 2; kh++)
        #pragma unroll
        for (int r = 0; r < 4; r++) rl[kh][r] = 0.f;
    const float scale = 0.015625f;           // 1/sqrt(4096)
    int jbase = jc * 1024;
    int sr = t >> 2, sch = t & 3;
    uint4 pf[4];
    {   const uint4* src = (const uint4*)(PTb + (long long)(jbase + sr) * CO + sch * 32);
        #pragma unroll
        for (int i = 0; i < 4; i++) pf[i] = src[i];
    }
    for (int jt = 0; jt < 16; jt++){
        int cur = jt & 1;
        {   uint4* dst = (uint4*)&Ps[cur][sr][sch * 32];
            #pragma unroll
            for (int i = 0; i < 4; i++) dst[i] = pf[i];
        }
        __syncthreads();
        if (jt < 15){
            const uint4* src = (const uint4*)(PTb + (long long)(jbase + (jt+1)*64 + sr) * CO + sch * 32);
            #pragma unroll
            for (int i = 0; i < 4; i++) pf[i] = src[i];
        }
        #pragma unroll
        for (int kh = 0; kh < 2; kh++){
            float sv[4][4];
            #pragma unroll
            for (int ct = 0; ct < 4; ct++){
                f4v acc = {0.f,0.f,0.f,0.f};
                #pragma unroll
                for (int ks = 0; ks < 4; ks++){
                    s8v bv = *(const s8v*)&Ps[cur][ct*16 + m][q*8 + ks*32];
                    acc = __builtin_amdgcn_mfma_f32_16x16x32_bf16(a[kh][ks], bv, acc, 0, 0, 0);
                }
                #pragma unroll
                for (int r = 0; r < 4; r++) sv[ct][r] = acc[r] * scale;
            }
            #pragma unroll
            for (int r = 0; r < 4; r++){
                float se = __expf(sv[0][r]) + __expf(sv[1][r])
                         + __expf(sv[2][r]) + __expf(sv[3][r]);
                #pragma unroll
                for (int msk = 1; msk < 16; msk <<= 1) se += __shfl_xor(se, msk);
                rl[kh][r] += se;
            }
        }
    }
    if (m == 0){
        #pragma unroll
        for (int kh = 0; kh < 2; kh++)
            #pragma unroll
            for (int r = 0; r < 4; r++){
                int k = k0 + kh*64 + w*16 + q*4 + r;
                lpart[(long long)jc * (NB*HW) + (long long)b*HW + k] = rl[kh][r];
            }
    }
}

// ---------------- attention pass 2 (split-k x2): wave-private DMA pipeline, counted vmcnt ----------------
__global__ __launch_bounds__(256)
void k_attn_apply2(const unsigned short* __restrict__ QT,
                   const unsigned short* __restrict__ PT,
                   const unsigned short* __restrict__ Pb,
                   const float* __restrict__ lpart,
                   float* __restrict__ Lp){
    int b = blockIdx.z, kc = blockIdx.y, j0 = blockIdx.x * 64;
    const unsigned short* QTb = QT + (long long)b * HW * CO;
    const unsigned short* PTb = PT + (long long)b * HW * CO;
    const unsigned short* Pbb = Pb + (long long)b * CO * HW;
    __shared__ __align__(16) unsigned short Qks[64*128];  // 16 KB
    __shared__ __align__(16) unsigned short Pcs[128*64];  // 16 KB
    __shared__ unsigned short Et[64][72];
    __shared__ float Il[2048];
    int t = threadIdx.x;
    int w = t >> 6, lane = t & 63, m = lane & 15, q = lane >> 4;
    int kbase = kc * 2048;
    int rl4 = lane >> 4;                                  // Qks DMA: row within 4-row group
    int rl8 = lane >> 3;                                  // Pcs DMA: row within 8-row group
    int gch8 = (lane & 7) ^ rl8;                          // Pcs source chunk
    {   // fused stat combine (plain sum, no-max): Il for this block's k-range
        #pragma unroll
        for (int r = 0; r < 8; r++){
            int kl = t*8 + r;
            long long gi = (long long)b*HW + kbase + kl;
            float l = lpart[gi] + lpart[gi+16384] + lpart[gi+32768] + lpart[gi+49152];
            Il[kl] = 1.f / l;
        }
    }
    {   // stage PT j-tile into Qks (4 issues/wave) then Pcs(kt=0) (4 issues/wave)
        #pragma unroll
        for (int i = 0; i < 4; i++){
            int rowb = w*16 + i*4;
            int gch = (lane & 15) ^ ((rowb & 15) + rl4);
            lds_dma16(PTb + (long long)(j0 + rowb + rl4)*CO + gch*8, &Qks[rowb*128]);
        }
        #pragma unroll
        for (int i = 0; i < 4; i++){
            int rowb = w*32 + i*8;
            lds_dma16(Pbb + (long long)(rowb + rl8)*HW + kbase + gch8*8, &Pcs[rowb*64]);
        }
    }
    asm volatile("s_waitcnt vmcnt(4) lgkmcnt(0)" ::: "memory");  // PT done; Il written; Pcs(0) in flight
    __builtin_amdgcn_s_barrier();                                // publish PT + Il
    __builtin_amdgcn_sched_barrier(0);
    s8v bj[4][4];
    #pragma unroll
    for (int ct = 0; ct < 4; ct++)
        #pragma unroll
        for (int ks = 0; ks < 4; ks++)
            bj[ct][ks] = *(const s8v*)&Qks[(ct*16 + m)*128 + ((q + 4*ks) ^ m)*8];
    asm volatile("s_waitcnt lgkmcnt(0)" ::: "memory");           // bj in regs
    __builtin_amdgcn_s_barrier();                                // all waves done reading PT tile
    __builtin_amdgcn_sched_barrier(0);
    {   // Qks <- QT k-tile for kt=0
        #pragma unroll
        for (int i = 0; i < 4; i++){
            int rowb = w*16 + i*4;
            int gch = (lane & 15) ^ ((rowb & 15) + rl4);
            lds_dma16(QTb + (long long)(kbase + rowb + rl4)*CO + gch*8, &Qks[rowb*128]);
        }
    }
    f4v accL[2][4];
    #pragma unroll
    for (int mt = 0; mt < 2; mt++)
        #pragma unroll
        for (int ct = 0; ct < 4; ct++){ f4v z = {0.f,0.f,0.f,0.f}; accL[mt][ct] = z; }
    const float scale = 0.015625f;
    for (int kt = 0; kt < 32; kt++){
        int k0 = kbase + kt*64;
        // wait this wave's Qks(kt) (oldest); Pcs stays in flight (kt=0: queue order differs -> drain)
        if (kt == 0) asm volatile("s_waitcnt vmcnt(0)" ::: "memory");
        else         asm volatile("s_waitcnt vmcnt(4)" ::: "memory");
        __builtin_amdgcn_sched_barrier(0);
        // ---- QK phase (own Qks rows) ----
        s8v aS[4];
        #pragma unroll
        for (int ks = 0; ks < 4; ks++)
            aS[ks] = *(const s8v*)&Qks[(w*16 + m)*128 + ((q + 4*ks) ^ m)*8];
        float il[4];
        #pragma unroll
        for (int r = 0; r < 4; r++) il[r] = Il[kt*64 + w*16 + q*4 + r];
        #pragma unroll
        for (int ct = 0; ct < 4; ct++){
            f4v s = {0.f,0.f,0.f,0.f};
            #pragma unroll
            for (int ks = 0; ks < 4; ks++)
                s = __builtin_amdgcn_mfma_f32_16x16x32_bf16(aS[ks], bj[ct][ks], s, 0, 0, 0);
            s4v e4;
            #pragma unroll
            for (int r = 0; r < 4; r++)
                e4[r] = (short)f2bf(__expf(s[r]*scale) * il[r]);
            *(s4v*)&Et[ct*16 + m][w*16 + q*4] = e4;
        }
        // prefetch own Qks rows for kt+1 (aS consumed via MFMA lgkm waits)
        if (kt+1 < 32){
            #pragma unroll
            for (int i = 0; i < 4; i++){
                int rowb = w*16 + i*4;
                int gch = (lane & 15) ^ ((rowb & 15) + rl4);
                lds_dma16(QTb + (long long)(k0 + 64 + rowb + rl4)*CO + gch*8, &Qks[rowb*128]);
            }
        }
        asm volatile("s_waitcnt lgkmcnt(0)" ::: "memory");   // Et committed
        __builtin_amdgcn_s_barrier();                        // publish Et (DMAs stay in flight)
        __builtin_amdgcn_sched_barrier(0);
        // wait this wave's Pcs(kt) (oldest); Qks(kt+1) stays in flight
        asm volatile("s_waitcnt vmcnt(4)" ::: "memory");
        __builtin_amdgcn_sched_barrier(0);
        // ---- PV phase (own Pcs rows, shared Et) ----
        s8v aP[2][2];
        #pragma unroll
        for (int mt = 0; mt < 2; mt++)
            #pragma unroll
            for (int ks2 = 0; ks2 < 2; ks2++)
                aP[mt][ks2] = *(const s8v*)&Pcs[(w*32 + mt*16 + m)*64 + ((q + 4*ks2) ^ (m&7))*8];
        #pragma unroll
        for (int ct = 0; ct < 4; ct++){
            s8v bE0 = *(const s8v*)&Et[ct*16 + m][q*8];
            s8v bE1 = *(const s8v*)&Et[ct*16 + m][q*8 + 32];
            #pragma unroll
            for (int mt = 0; mt < 2; mt++){
                accL[mt][ct] = __builtin_amdgcn_mfma_f32_16x16x32_bf16(aP[mt][0], bE0, accL[mt][ct], 0, 0, 0);
                accL[mt][ct] = __builtin_amdgcn_mfma_f32_16x16x32_bf16(aP[mt][1], bE1, accL[mt][ct], 0, 0, 0);
            }
        }
        // prefetch own Pcs rows for kt+1 (aP consumed)
        if (kt+1 < 32){
            #pragma unroll
            for (int i = 0; i < 4; i++){
                int rowb = w*32 + i*8;
                lds_dma16(Pbb + (long long)(rowb + rl8)*HW + k0 + 64 + gch8*8, &Pcs[rowb*64]);
            }
        }
        __builtin_amdgcn_s_barrier();                        // Et(kt) reads done before Et(kt+1) writes
        __builtin_amdgcn_sched_barrier(0);
    }
    float* Lpb = Lp + ((long long)(kc*NB + b) * CO) * HW;
    #pragma unroll
    for (int mt = 0; mt < 2; mt++)
        #pragma unroll
        for (int ct = 0; ct < 4; ct++)
            #pragma unroll
            for (int r = 0; r < 4; r++){
                int c = w*32 + mt*16 + q*4 + r;
                Lpb[(long long)c*HW + j0 + ct*16 + m] = accL[mt][ct][r];
            }
}

// ---------------- fused: O = xa + sum(Lp) -> bf16 B-tile -> conv2 -> out f32 (DMA A-staging) ----------------
__global__ __launch_bounds__(256)
void k_outfused(const unsigned short* __restrict__ A,    // w_c2 [256][128] bf16
                const float* __restrict__ Lp, const float* __restrict__ xa,
                const float* __restrict__ bias, float* __restrict__ out){
    int b = blockIdx.y, j0 = blockIdx.x*32;
    __shared__ unsigned short Bs[32][136];
    __shared__ __align__(16) char pool[256*68*2];   // phase1: Bsf[128][33] f32; phase2: As[256*64] bf16
    int t = threadIdx.x;
    // phase 1: O tile f32 = xa + 2 partials (coalesced c-rows)
    {
        float* Bsf = (float*)pool;
        int c = t>>1, jh = t&1;
        long long base = ((long long)b*CO + c)*HW + j0 + jh*16;
        const long long csz = (long long)NB*CO*HW;
        float v[16];
        #pragma unroll
        for (int r = 0; r < 16; r++) v[r] = xa[base + r];
        #pragma unroll
        for (int pidx = 0; pidx < 2; pidx++){
            const float* src = Lp + pidx*csz + base;
            #pragma unroll
            for (int r = 0; r < 16; r++) v[r] += src[r];
        }
        #pragma unroll
        for (int r = 0; r < 16; r++) Bsf[c*33 + jh*16 + r] = v[r];
    }
    __syncthreads();
    // transpose to bf16 B-tile [j][c]
    {
        const float* Bsf = (const float*)pool;
        int j = t>>3, cs = t&7;
        #pragma unroll
        for (int r = 0; r < 16; r++){
            int c = cs*16 + r;
            Bs[j][c] = f2bf(Bsf[c*33 + j]);
        }
    }
    __syncthreads();
    // phase 2: GEMM M=256 x N=32 x K=128, A staged via DMA (pitch 64, swizzled)
    unsigned short* As = (unsigned short*)pool;
    int w = t>>6, lane = t&63, m = lane&15, q = lane>>4;
    int rl8 = lane>>3, gch = (lane&7) ^ rl8, rsw = m&7;
    f4v acc[4][2];
    #pragma unroll
    for (int ms = 0; ms < 4; ms++)
        #pragma unroll
        for (int ct = 0; ct < 2; ct++){ f4v z = {0.f,0.f,0.f,0.f}; acc[ms][ct] = z; }
    for (int k0 = 0; k0 < 128; k0 += 64){
        __syncthreads();                                  // prior reads of pool/As done
        #pragma unroll
        for (int i = 0; i < 8; i++){
            int ar = w*64 + i*8;
            lds_dma16(A + (long long)(ar + rl8)*128 + k0 + gch*8, &As[ar*64]);
        }
        __syncthreads();                                  // vmcnt(0) drained -> visible
        #pragma unroll
        for (int ks = 0; ks < 2; ks++){
            s8v bfr[2];
            #pragma unroll
            for (int ct = 0; ct < 2; ct++) bfr[ct] = *(const s8v*)&Bs[ct*16+m][k0 + ks*32 + q*8];
            #pragma unroll
            for (int ms = 0; ms < 4; ms++){
                s8v afr = *(const s8v*)&As[(w*64 + ms*16 + m)*64 + ((q + 4*ks) ^ rsw)*8];
                #pragma unroll
                for (int ct = 0; ct < 2; ct++)
                    acc[ms][ct] = __builtin_amdgcn_mfma_f32_16x16x32_bf16(afr, bfr[ct], acc[ms][ct], 0,0,0);
            }
        }
    }
    #pragma unroll
    for (int ct = 0; ct < 2; ct++){
        int p = j0 + ct*16 + m;
        #pragma unroll
        for (int ms = 0; ms < 4; ms++)
            #pragma unroll
            for (int r = 0; r < 4; r++){
                int c = w*64 + ms*16 + q*4 + r;
                out[((long long)b*256 + c)*HW + p] = acc[ms][ct][r] + bias[c];
            }
    }
}

extern "C" void kernel_launch(void* const* d_in, const int* in_sizes, int n_in,
                              void* d_out, int out_size, void* d_ws, size_t ws_size,
                              hipStream_t stream) {
    const float* x       = (const float*)d_in[0];
    const float* conv1_w = (const float*)d_in[1];
    const float* conv1_b = (const float*)d_in[2];
    const float* conv2_w = (const float*)d_in[3];
    const float* conv2_b = (const float*)d_in[4];
    const float* cw_w1   = (const float*)d_in[5];
    const float* cw_b1   = (const float*)d_in[6];
    const float* cw_g    = (const float*)d_in[7];
    const float* cw_bt   = (const float*)d_in[8];
    const float* cw_w2   = (const float*)d_in[9];
    const float* cw_b2   = (const float*)d_in[10];
    const float* a0_w    = (const float*)d_in[11];
    const float* a0_g    = (const float*)d_in[12];
    const float* a0_b    = (const float*)d_in[13];
    const float* a1_w    = (const float*)d_in[14];
    const float* a1_g    = (const float*)d_in[15];
    const float* a1_b    = (const float*)d_in[16];
    const float* a2_w    = (const float*)d_in[17];
    const float* a2_g    = (const float*)d_in[18];
    const float* a2_b    = (const float*)d_in[19];
    const float* a3_w    = (const float*)d_in[20];
    const float* a3_g    = (const float*)d_in[21];
    const float* a3_b    = (const float*)d_in[22];
    const float* ap_w    = (const float*)d_in[23];
    const float* ap_g    = (const float*)d_in[24];
    const float* ap_b    = (const float*)d_in[25];
    const float* pj_w    = (const float*)d_in[26];
    const float* pj_g    = (const float*)d_in[27];
    const float* pj_b    = (const float*)d_in[28];
    float* out = (float*)d_out;

    // ---- workspace layout ----
    float* ws    = (float*)d_ws;
    float* avg   = ws;                  // 1024
    float* mx    = ws + 1024;           // 1024
    float* sv    = ws + 2048;           // 1024
    float* gp    = ws + 3072;           // 1024
    float* zbuf  = ws + 4096;           // 256 f32 zero-page for OOB DMA
    float* xa    = ws + 37888;          // 2,097,152
    float* lpart = xa + 2097152;        // 65536
    unsigned short* sb = (unsigned short*)(ws + 4232192);
    unsigned short* xT    = sb;                    // 4,194,304
    unsigned short* xcT   = sb + 4194304;          // 4,194,304
    unsigned short* catT  = sb + 8388608;          // 20,971,520
    unsigned short* projT = sb + 29360128;         // 4,194,304
    unsigned short* P_bf  = sb + 33554432;         // 2,097,152
    unsigned short* PT_bf = sb + 35651584;         // 2,097,152
    unsigned short* QT_bf = sb + 37748736;         // 2,097,152
    unsigned short* w_c1  = sb + 41943040;         // 32768
    unsigned short* w_a0  = sb + 41975808;         // 65536
    unsigned short* w_pj  = sb + 42041344;         // 327680
    unsigned short* w_c2  = sb + 42369024;         // 32768
    unsigned short* w_d3  = sb + 42401792;         // 589824
    unsigned short* w_d6  = sb + 42991616;         // 589824
    unsigned short* w_d9  = sb + 43581440;         // 589824
    float* Lp = (float*)catT;           // alias: catT dead after proj (16.8MB in 42MB region)

    // ---- rowstats + all weight casts (one launch) ----
    k_pre<<<dim3(9728), 256, 0, stream>>>(x, avg, mx,
                                          conv1_w, a0_w, pj_w, conv2_w, a1_w, a2_w, a3_w,
                                          w_c1, w_a0, w_pj, w_c2, w_d3, w_d6, w_d9);
    k_cw<<<dim3(NB), 256, 0, stream>>>(avg, mx, cw_w1, cw_b1, cw_g, cw_bt, cw_w2, cw_b2, sv, gp, zbuf);

    // ---- x -> xT bf16 and xcT ----
    k_xT<<<dim3(64, 4, NB), 256, 0, stream>>>(x, sv, xT, xcT);

    // ---- x1 = conv1(x)+b -> P_bf/PT_bf ----
    k_conv1m<<<dim3(128, NB), 256, 0, stream>>>(w_c1, xT, conv1_b, PT_bf, P_bf, nullptr);

    // ---- ASPP: 3 dilated convs + a0 + pool/bcast in ONE launch (N=256, dbuf counted-vmcnt) ----
    k_aspp<<<dim3(16, 5, NB), 512, 0, stream>>>(w_a0, w_d3, w_d6, w_d9, xcT,
                                                a0_g, a0_b, a1_g, a1_b, a2_g, a2_b, a3_g, a3_b,
                                                gp, ap_w, ap_g, ap_b, zbuf, catT);

    // ---- proj = GELU(LN(conv1x1(cat))) -> projT bf16 (pipelined dbuf DMA) ----
    k_branch1<<<dim3(128, NB), 512, 0, stream>>>(w_pj, 1280, catT, pj_g, pj_b, projT, 256, 0);

    // ---- xa = conv1(proj)+b -> xa f32 + QT_bf ----
    k_conv1m<<<dim3(128, NB), 256, 0, stream>>>(w_c1, projT, conv1_b, QT_bf, nullptr, xa);

    // ---- attention (no-max softmax; comb fused into apply; kc-split = 2; counted-vmcnt apply) ----
    k_attn_stats3<<<dim3(32, 4, NB), 256, 0, stream>>>(QT_bf, PT_bf, lpart);
    k_attn_apply2<<<dim3(64, 2, NB), 256, 0, stream>>>(QT_bf, PT_bf, P_bf, lpart, Lp);

    // ---- out = conv2(xa + sum Lp) + b (fused) ----
    k_outfused<<<dim3(128, NB), 256, 0, stream>>>(w_c2, Lp, xa, conv2_b, out);

    (void)in_sizes; (void)n_in; (void)out_size; (void)ws_size;
}

// Round 10
// 371.948 us; speedup vs baseline: 1.0653x; 1.0332x over previous
//
#include <hip/hip_runtime.h>
#include <hip/hip_bf16.h>
#include <math.h>

// Problem constants (B=4, Cin=256, Cout=128, H=W=64)
#define NB 4
#define CI 256
#define CO 128
#define HW 4096

typedef __attribute__((ext_vector_type(8))) short s8v;   // 8 bf16 = 4 VGPRs (MFMA A/B frag)
typedef __attribute__((ext_vector_type(4))) short s4v;
typedef __attribute__((ext_vector_type(4))) float f4v;   // MFMA C/D frag

__device__ __forceinline__ unsigned short f2bf(float f){
    __hip_bfloat16 h = __float2bfloat16(f);   // RNE
    return *reinterpret_cast<unsigned short*>(&h);
}

// async global->LDS DMA, 16B per lane; LDS dest = wave-uniform base + lane*16
__device__ __forceinline__ void lds_dma16(const void* g, void* l){
    __builtin_amdgcn_global_load_lds((const __attribute__((address_space(1))) unsigned int*)g,
                                     (__attribute__((address_space(3))) unsigned int*)l,
                                     16, 0, 0);
}

// A&S 7.1.26 erf (max abs err 1.5e-7)
__device__ __forceinline__ float gelu_f(float x){
    float z  = x * 0.70710678118654752f;
    float az = fabsf(z);
    float tt = 1.f / (1.f + 0.3275911f * az);
    float poly = tt*(0.254829592f + tt*(-0.284496736f + tt*(1.421413741f +
                 tt*(-1.453152027f + tt*1.061405429f))));
    float erfv = 1.f - poly * __expf(-az*az);
    erfv = (z < 0.f) ? -erfv : erfv;
    return 0.5f * x * (1.f + erfv);
}

// ---------------- fused: per-channel avg/max (blocks 0..1023) + ALL weight casts ----------------
__global__ void k_pre(const float* __restrict__ x, float* __restrict__ avg, float* __restrict__ mx,
                      const float* __restrict__ c1, const float* __restrict__ a0,
                      const float* __restrict__ pj, const float* __restrict__ c2,
                      const float* __restrict__ d3, const float* __restrict__ d6,
                      const float* __restrict__ d9,
                      unsigned short* __restrict__ w_c1, unsigned short* __restrict__ w_a0,
                      unsigned short* __restrict__ w_pj, unsigned short* __restrict__ w_c2,
                      unsigned short* __restrict__ w_d3, unsigned short* __restrict__ w_d6,
                      unsigned short* __restrict__ w_d9){
    int blk = blockIdx.x;
    int t = threadIdx.x;
    if (blk < 1024){
        const float* p = x + (long long)blk * HW;
        float s = 0.f, m = -1e30f;
        for (int i = t; i < HW; i += 256){ float v = p[i]; s += v; m = fmaxf(m, v); }
        __shared__ float ss[256], sm[256];
        ss[t] = s; sm[t] = m; __syncthreads();
        for (int o = 128; o > 0; o >>= 1){
            if (t < o){ ss[t] += ss[t+o]; sm[t] = fmaxf(sm[t], sm[t+o]); }
            __syncthreads();
        }
        if (t == 0){ avg[blk] = ss[0] / (float)HW; mx[blk] = sm[0]; }
        return;
    }
    int i = (blk - 1024)*256 + t;
    if (i < 458752){
        if (i < 32768)        w_c1[i]        = f2bf(c1[i]);
        else if (i < 98304)   w_a0[i-32768]  = f2bf(a0[i-32768]);
        else if (i < 425984)  w_pj[i-98304]  = f2bf(pj[i-98304]);
        else                  w_c2[i-425984] = f2bf(c2[i-425984]);
    } else {
        int j = i - 458752;
        int which = j / 589824;
        int l = j - which*589824;
        int tap = l >> 16, rem = l & 65535, o = rem >> 8, ci = rem & 255;
        const float* src = (which==0) ? d3 : ((which==1) ? d6 : d9);
        unsigned short* dst = (which==0) ? w_d3 : ((which==1) ? w_d6 : w_d9);
        dst[l] = f2bf(src[o*2304 + ci*9 + tap]);
    }
}

// ---------------- ChannelWeighting; also gp = avg*(1+s); block 0 zeroes the DMA zero-page ----------------
__global__ void k_cw(const float* __restrict__ avg, const float* __restrict__ mx,
                     const float* __restrict__ w1, const float* __restrict__ b1,
                     const float* __restrict__ lng, const float* __restrict__ lnb,
                     const float* __restrict__ w2, const float* __restrict__ b2,
                     float* __restrict__ sv, float* __restrict__ gp,
                     float* __restrict__ zb){
    int b = blockIdx.x, t = threadIdx.x;
    if (b == 0) zb[t] = 0.f;                 // 1 KB zero-page for OOB DMA lanes
    __shared__ float o_s[256];
    __shared__ float h_s[128];
    __shared__ float stat[2];
    float a = avg[b*256 + t];
    o_s[t] = fabsf(a - mx[b*256 + t]) * a;
    __syncthreads();
    if (t < 128){
        float h = b1[t];
        for (int i = 0; i < 256; i++) h += o_s[i] * w1[t*256 + i];
        h_s[t] = h;
    }
    __syncthreads();
    if (t == 0){
        float s = 0.f, s2 = 0.f;
        for (int j = 0; j < 128; j++){ s += h_s[j]; s2 += h_s[j]*h_s[j]; }
        float mean = s / 128.f;
        float var  = s2 / 128.f - mean*mean;
        stat[0] = mean; stat[1] = rsqrtf(var + 1e-5f);
    }
    __syncthreads();
    if (t < 128) h_s[t] = lng[t] * ((h_s[t] - stat[0]) * stat[1]) + lnb[t];
    __syncthreads();
    float z = b2[t];
    for (int j = 0; j < 128; j++) z += h_s[j] * w2[t*128 + j];
    float sig = 1.f / (1.f + __expf(-z));
    sv[b*256 + t] = sig;
    gp[b*256 + t] = a * (1.f + sig);
}

// ---------------- x -> xT bf16 [b][HW][256] and xcT = bf16(x*(1+s)) ----------------
__global__ void k_xT(const float* __restrict__ x, const float* __restrict__ sv,
                     unsigned short* __restrict__ xT, unsigned short* __restrict__ xcT){
    int b = blockIdx.z, c0 = blockIdx.y*64, h0 = blockIdx.x*64;
    __shared__ unsigned short T1[64][66], T2[64][66];
    int t = threadIdx.x;
    int hl = t & 63, cs = t >> 6;
    #pragma unroll
    for (int r = 0; r < 16; r++){
        int c = cs*16 + r;
        float v = x[((long long)b*256 + c0 + c)*HW + h0 + hl];
        float sc = 1.f + sv[b*256 + c0 + c];
        T1[c][hl] = f2bf(v);
        T2[c][hl] = f2bf(v*sc);
    }
    __syncthreads();
    int cl = t & 63, hs = t >> 6;
    #pragma unroll
    for (int r = 0; r < 16; r++){
        int h = hs*16 + r;
        long long o = ((long long)b*HW + h0 + h)*256 + c0 + cl;
        xT[o]  = T1[cl][h];
        xcT[o] = T2[cl][h];
    }
}

// ============ 8-wave epilogue, N=32: LN(256ch)+GELU -> transposed bf16 ============
__device__ __forceinline__ void ln_epi32(f4v acc[2][2],
        int b, int n0, int w, int lane, int m, int q, int t,
        const float* Gs, const float* Bts,
        float (*Psum)[32], float (*Psq)[32], float* Mn, float* Iv,
        unsigned short* __restrict__ outT, int outPitch, int colOff){
    float ls[2], ls2[2];
    #pragma unroll
    for (int ct = 0; ct < 2; ct++){
        float s = 0.f, s2 = 0.f;
        #pragma unroll
        for (int ms = 0; ms < 2; ms++)
            #pragma unroll
            for (int r = 0; r < 4; r++){ float v = acc[ms][ct][r]; s += v; s2 += v*v; }
        ls[ct] = s; ls2[ct] = s2;
    }
    #pragma unroll
    for (int ct = 0; ct < 2; ct++){
        ls[ct]  += __shfl_xor(ls[ct], 16);  ls[ct]  += __shfl_xor(ls[ct], 32);
        ls2[ct] += __shfl_xor(ls2[ct], 16); ls2[ct] += __shfl_xor(ls2[ct], 32);
    }
    if (lane < 16){
        #pragma unroll
        for (int ct = 0; ct < 2; ct++){ Psum[w][ct*16+lane] = ls[ct]; Psq[w][ct*16+lane] = ls2[ct]; }
    }
    __syncthreads();
    if (t < 32){
        float s = 0.f, s2 = 0.f;
        #pragma unroll
        for (int ww = 0; ww < 8; ww++){ s += Psum[ww][t]; s2 += Psq[ww][t]; }
        float mean = s * (1.f/256.f);
        Mn[t] = mean;
        Iv[t] = rsqrtf(s2*(1.f/256.f) - mean*mean + 1e-6f);
    }
    __syncthreads();
    #pragma unroll
    for (int ct = 0; ct < 2; ct++){
        int p = ct*16 + m;
        float mean = Mn[p], inv = Iv[p];
        long long rowb = ((long long)b*HW + n0 + p)*outPitch + colOff;
        #pragma unroll
        for (int ms = 0; ms < 2; ms++){
            s4v o4;
            #pragma unroll
            for (int r = 0; r < 4; r++){
                int c = w*32 + ms*16 + q*4 + r;
                float h = Gs[c]*((acc[ms][ct][r] - mean)*inv) + Bts[c];
                o4[r] = (short)f2bf(gelu_f(h));
            }
            *(s4v*)(outT + rowb + w*32 + ms*16 + q*4) = o4;
        }
    }
}

// ---------------- unified ASPP v3 (round-2/6 proven): N=128, global_load_lds staging, swizzled read ----------------
__global__ __launch_bounds__(512, 4)
void k_aspp(const unsigned short* __restrict__ w_a0, const unsigned short* __restrict__ w_d3,
            const unsigned short* __restrict__ w_d6, const unsigned short* __restrict__ w_d9,
            const unsigned short* __restrict__ BT,
            const float* __restrict__ a0_g, const float* __restrict__ a0_b,
            const float* __restrict__ a1_g, const float* __restrict__ a1_b,
            const float* __restrict__ a2_g, const float* __restrict__ a2_b,
            const float* __restrict__ a3_g, const float* __restrict__ a3_b,
            const float* __restrict__ gp, const float* __restrict__ ap_w,
            const float* __restrict__ ap_g, const float* __restrict__ ap_b,
            const float* __restrict__ zbuf,
            unsigned short* __restrict__ catT){
    int br = blockIdx.y, b = blockIdx.z;
    int t = threadIdx.x;
    __shared__ __align__(16) unsigned short As[256*64];   // 32 KB, pitch 64 shorts (128 B)
    __shared__ __align__(16) unsigned short Bs[128*64];   // 16 KB (epilogue stats aliased here)
    __shared__ float Gs[256], Bts[256];
    if (br == 4){
        // ---- pool + broadcast ----
        int p0 = blockIdx.x*128;
        float* z_s = (float*)As;                          // 256 f32
        unsigned short* bp_s = As + 2048;                 // 256 bf16
        float* stat = (float*)(As + 4096);
        if (t < 256){
            float z = 0.f;
            for (int c = 0; c < 256; c++) z += gp[b*256 + c] * ap_w[t*256 + c];
            z_s[t] = z;
        }
        __syncthreads();
        if (t == 0){
            float s = 0.f, s2 = 0.f;
            for (int c = 0; c < 256; c++){ s += z_s[c]; s2 += z_s[c]*z_s[c]; }
            float mean = s / 256.f, var = s2 / 256.f - mean*mean;
            stat[0] = mean; stat[1] = rsqrtf(var + 1e-6f);
        }
        __syncthreads();
        if (t < 256){
            float h = ap_g[t] * ((z_s[t] - stat[0]) * stat[1]) + ap_b[t];
            bp_s[t] = f2bf(gelu_f(h));
        }
        __syncthreads();
        for (int it = 0; it < 8; it++){
            int i = it*512 + t;
            int pl = i >> 5, cj = (i & 31) * 8;
            s8v v8;
            #pragma unroll
            for (int k2 = 0; k2 < 8; k2++) v8[k2] = (short)bp_s[cj + k2];
            *(s8v*)(catT + ((long long)b*HW + p0 + pl)*1280 + 1024 + cj) = v8;
        }
        return;
    }
    // ---- conv branches (br0 = 1-tap case: tap=0, d=0) ----
    int n0 = blockIdx.x * 128;
    const unsigned short* BTb = BT + (long long)b*HW*256;
    const unsigned short* A  = (br==0) ? w_a0 : (br==1) ? w_d3 : (br==2) ? w_d6 : w_d9;
    const float* g   = (br==0) ? a0_g : (br==1) ? a1_g : (br==2) ? a2_g : a3_g;
    const float* bta = (br==0) ? a0_b : (br==1) ? a1_b : (br==2) ? a2_b : a3_b;
    int d    = (br==0) ? 0 : (br==1) ? 3 : (br==2) ? 6 : 9;
    int NS   = (br==0) ? 4 : 36;                          // (tap,kc) stages, kc fastest
    if (t < 256){ Gs[t] = g[t]; Bts[t] = bta[t]; }

    int w = t>>6, lane = t&63, m = lane&15, q = lane>>4;
    int wr = w>>1, wc = w&1;                              // wave tile: rows wr*64.., cols wc*64..
    int rsw = m&7;                                        // read-side swizzle key
    int rl8 = lane>>3;                                    // lane's row within an 8-row DMA group
    int gch = (lane&7) ^ rl8;                             // pre-swizzled source chunk
    int aoff = rl8*256 + gch*8;                           // per-lane A source offset (shorts)
    int y0 = n0 >> 6;                                     // image row of first tile position

    f4v acc[4][4];
    #pragma unroll
    for (int ms = 0; ms < 4; ms++)
        #pragma unroll
        for (int ct = 0; ct < 4; ct++){ f4v z = {0.f,0.f,0.f,0.f}; acc[ms][ct] = z; }

    for (int s = 0; s < NS; ++s){
        int tap = s>>2, kc = s&3;
        int dy = tap/3 - 1, dx = tap%3 - 1;
        // ---- A: 256 rows x 64 ch; wave w stages rows w*32..w*32+31 (4 DMA issues) ----
        const unsigned short* abase = A + tap*65536 + kc*64 + aoff;
        #pragma unroll
        for (int i = 0; i < 4; i++){
            int row0 = w*32 + i*8;
            lds_dma16(abase + row0*256, &As[row0*64]);
        }
        // ---- B: 128 positions x 64 ch; wave w stages rows w*16..w*16+15 (2 DMA issues) ----
        int xadd = rl8 + dx*d;
        #pragma unroll
        for (int i = 0; i < 2; i++){
            int bn0 = w*16 + i*8;
            int yy = y0 + (bn0>>6) + dy*d;
            int xs = (bn0 & 63) + xadd;
            const unsigned short* gsrc = ((unsigned)yy < 64u && (unsigned)xs < 64u)
                ? (BTb + (long long)(yy*64 + xs)*256 + kc*64 + gch*8)
                : (const unsigned short*)zbuf;
            lds_dma16(gsrc, &Bs[bn0*64]);
        }
        __syncthreads();                                  // vmcnt(0) drained here -> data visible
        #pragma unroll
        for (int ks = 0; ks < 2; ks++){
            s8v bfr[4];
            #pragma unroll
            for (int ct = 0; ct < 4; ct++)
                bfr[ct] = *(const s8v*)&Bs[(wc*64 + ct*16 + m)*64 + ((q + 4*ks) ^ rsw)*8];
            #pragma unroll
            for (int ms = 0; ms < 4; ms++){
                s8v afr = *(const s8v*)&As[(wr*64 + ms*16 + m)*64 + ((q + 4*ks) ^ rsw)*8];
                #pragma unroll
                for (int ct = 0; ct < 4; ct++)
                    acc[ms][ct] = __builtin_amdgcn_mfma_f32_16x16x32_bf16(afr, bfr[ct], acc[ms][ct], 0,0,0);
            }
        }
        __syncthreads();                                  // all LDS reads done before next DMA
    }
    // ---- epilogue: LN over 256 channels per position (128 positions), GELU, store ----
    float* Psum = (float*)Bs;                             // [4][128]
    float* Psq  = Psum + 512;                             // [4][128]
    float* Mn   = Psq  + 512;                             // [128]
    float* Iv   = Mn   + 128;                             // [128]
    #pragma unroll
    for (int ct = 0; ct < 4; ct++){
        float s = 0.f, s2 = 0.f;
        #pragma unroll
        for (int ms = 0; ms < 4; ms++)
            #pragma unroll
            for (int r = 0; r < 4; r++){ float v = acc[ms][ct][r]; s += v; s2 += v*v; }
        s  += __shfl_xor(s, 16);  s  += __shfl_xor(s, 32);
        s2 += __shfl_xor(s2, 16); s2 += __shfl_xor(s2, 32);
        if (lane < 16){
            Psum[wr*128 + wc*64 + ct*16 + lane] = s;
            Psq [wr*128 + wc*64 + ct*16 + lane] = s2;
        }
    }
    __syncthreads();
    if (t < 128){
        float s  = Psum[t] + Psum[128+t] + Psum[256+t] + Psum[384+t];
        float s2 = Psq [t] + Psq [128+t] + Psq [256+t] + Psq [384+t];
        float mean = s * (1.f/256.f);
        Mn[t] = mean;
        Iv[t] = rsqrtf(s2*(1.f/256.f) - mean*mean + 1e-6f);
    }
    __syncthreads();
    #pragma unroll
    for (int ct = 0; ct < 4; ct++){
        int p = wc*64 + ct*16 + m;
        float mean = Mn[p], inv = Iv[p];
        long long rowb = ((long long)b*HW + n0 + p)*1280 + br*256;
        #pragma unroll
        for (int ms = 0; ms < 4; ms++){
            s4v o4;
            #pragma unroll
            for (int r = 0; r < 4; r++){
                int c = wr*64 + ms*16 + q*4 + r;
                float h = Gs[c]*((acc[ms][ct][r] - mean)*inv) + Bts[c];
                o4[r] = (short)f2bf(gelu_f(h));
            }
            *(s4v*)(catT + rowb + wr*64 + ms*16 + q*4) = o4;
        }
    }
}

// ---------------- fused 1x1-conv (MFMA) + LN + GELU, 512 thr (proj) — pipelined dbuf DMA ----------------
__global__ __launch_bounds__(512)
void k_branch1(const unsigned short* __restrict__ A, int K,
               const unsigned short* __restrict__ BT,
               const float* __restrict__ g, const float* __restrict__ beta,
               unsigned short* __restrict__ outT, int outPitch, int colOff){
    int b = blockIdx.y, n0 = blockIdx.x*32;
    const unsigned short* BTb = BT + (long long)b*HW*K;
    __shared__ __align__(16) unsigned short As[2][256*64];  // 64 KB
    __shared__ __align__(16) unsigned short Bs[2][32*64];   // 8 KB
    __shared__ float Psum[8][32], Psq[8][32], Mn[32], Iv[32];
    __shared__ float Gs[256], Bts[256];
    int t = threadIdx.x, w = t>>6, lane = t&63, m = lane&15, q = lane>>4;
    int rl8 = lane>>3, gch = (lane&7) ^ rl8, rsw = m&7;
    if (t < 256){ Gs[t] = g[t]; Bts[t] = beta[t]; }
    f4v acc[2][2];
    #pragma unroll
    for (int ms = 0; ms < 2; ms++)
        #pragma unroll
        for (int ct = 0; ct < 2; ct++){ f4v z = {0.f,0.f,0.f,0.f}; acc[ms][ct] = z; }
    const int NSt = K >> 6;                               // 20 for K=1280
    auto issue = [&](int s, int buf){
        int k0 = s*64;
        #pragma unroll
        for (int i = 0; i < 4; i++){
            int ar = w*32 + i*8;
            lds_dma16(A + (long long)(ar + rl8)*K + k0 + gch*8, &As[buf][ar*64]);
        }
        if (w < 4)
            lds_dma16(BTb + (long long)(n0 + w*8 + rl8)*K + k0 + gch*8, &Bs[buf][w*8*64]);
    };
    issue(0, 0);
    for (int s = 0; s < NSt; ++s){
        int cur = s & 1;
        if (s+1 < NSt){
            issue(s+1, cur^1);                            // prefetch into other buffer
            if (w < 4) asm volatile("s_waitcnt vmcnt(5)" ::: "memory");
            else       asm volatile("s_waitcnt vmcnt(4)" ::: "memory");
        } else {
            asm volatile("s_waitcnt vmcnt(0)" ::: "memory");
        }
        __builtin_amdgcn_s_barrier();                     // publish B(s) (no vmcnt drain)
        __builtin_amdgcn_sched_barrier(0);
        const unsigned short* Ac = &As[cur][0];
        const unsigned short* Bc = &Bs[cur][0];
        #pragma unroll
        for (int ks = 0; ks < 2; ks++){
            s8v bfr[2];
            #pragma unroll
            for (int ct = 0; ct < 2; ct++)
                bfr[ct] = *(const s8v*)&Bc[(ct*16 + m)*64 + ((q + 4*ks) ^ rsw)*8];
            #pragma unroll
            for (int ms = 0; ms < 2; ms++){
                s8v afr = *(const s8v*)&Ac[(w*32 + ms*16 + m)*64 + ((q + 4*ks) ^ rsw)*8];
                #pragma unroll
                for (int ct = 0; ct < 2; ct++)
                    acc[ms][ct] = __builtin_amdgcn_mfma_f32_16x16x32_bf16(afr, bfr[ct], acc[ms][ct], 0,0,0);
            }
        }
        __builtin_amdgcn_s_barrier();                     // buf[cur] reads done before s+2 reuses it
        __builtin_amdgcn_sched_barrier(0);
    }
    __syncthreads();
    ln_epi32(acc, b, n0, w, lane, m, q, t, Gs, Bts, Psum, Psq, Mn, Iv, outT, outPitch, colOff);
}

// ---------------- conv1 (M=128) MFMA, 256 thr, N=32, Kstage=64 — pipelined dbuf DMA ----------------
__global__ __launch_bounds__(256)
void k_conv1m(const unsigned short* __restrict__ A,      // [128][256] bf16
              const unsigned short* __restrict__ BT,     // [b][HW][256] bf16
              const float* __restrict__ bias,
              unsigned short* __restrict__ outT,         // [b][HW][128] bf16
              unsigned short* __restrict__ outC,         // [b][128][HW] bf16 or null
              float* __restrict__ outF){                 // [b][128][HW] f32 or null
    int b = blockIdx.y, n0 = blockIdx.x*32;
    const unsigned short* BTb = BT + (long long)b*HW*256;
    __shared__ __align__(16) unsigned short As[2][128*64];  // 32 KB
    __shared__ __align__(16) unsigned short Bs[2][32*64];   // 8 KB
    int t = threadIdx.x, w = t>>6, lane = t&63, m = lane&15, q = lane>>4;
    int rl8 = lane>>3, gch = (lane&7) ^ rl8, rsw = m&7;
    f4v acc[2][2];
    #pragma unroll
    for (int ms = 0; ms < 2; ms++)
        #pragma unroll
        for (int ct = 0; ct < 2; ct++){ f4v z = {0.f,0.f,0.f,0.f}; acc[ms][ct] = z; }
    auto issue = [&](int s, int buf){                     // 5 DMA/wave: 4 A + 1 B
        int k0 = s*64;
        #pragma unroll
        for (int i = 0; i < 4; i++){
            int ar = w*32 + i*8;
            lds_dma16(A + (long long)(ar + rl8)*256 + k0 + gch*8, &As[buf][ar*64]);
        }
        lds_dma16(BTb + (long long)(n0 + w*8 + rl8)*256 + k0 + gch*8, &Bs[buf][w*8*64]);
    };
    issue(0, 0);
    for (int s = 0; s < 4; ++s){
        int cur = s & 1;
        if (s+1 < 4){
            issue(s+1, cur^1);                            // prefetch into other buffer
            asm volatile("s_waitcnt vmcnt(5)" ::: "memory");  // stage-s's 5 done; s+1 in flight
        } else {
            asm volatile("s_waitcnt vmcnt(0)" ::: "memory");
        }
        __builtin_amdgcn_s_barrier();                     // publish stage s (no drain)
        __builtin_amdgcn_sched_barrier(0);
        const unsigned short* Ac = &As[cur][0];
        const unsigned short* Bc = &Bs[cur][0];
        #pragma unroll
        for (int ks = 0; ks < 2; ks++){
            s8v bfr[2];
            #pragma unroll
            for (int ct = 0; ct < 2; ct++)
                bfr[ct] = *(const s8v*)&Bc[(ct*16 + m)*64 + ((q + 4*ks) ^ rsw)*8];
            #pragma unroll
            for (int ms = 0; ms < 2; ms++){
                s8v afr = *(const s8v*)&Ac[(w*32 + ms*16 + m)*64 + ((q + 4*ks) ^ rsw)*8];
                #pragma unroll
                for (int ct = 0; ct < 2; ct++)
                    acc[ms][ct] = __builtin_amdgcn_mfma_f32_16x16x32_bf16(afr, bfr[ct], acc[ms][ct], 0,0,0);
            }
        }
        __builtin_amdgcn_s_barrier();                     // buf[cur] reads done before s+2 reuses it
        __builtin_amdgcn_sched_barrier(0);
    }
    #pragma unroll
    for (int ct = 0; ct < 2; ct++){
        int p = n0 + ct*16 + m;
        #pragma unroll
        for (int ms = 0; ms < 2; ms++){
            s4v o4;
            float vals[4];
            #pragma unroll
            for (int r = 0; r < 4; r++){
                int c = w*32 + ms*16 + q*4 + r;
                vals[r] = acc[ms][ct][r] + bias[c];
                o4[r] = (short)f2bf(vals[r]);
            }
            *(s4v*)(outT + ((long long)b*HW + p)*128 + w*32 + ms*16 + q*4) = o4;
            if (outC){
                #pragma unroll
                for (int r = 0; r < 4; r++){
                    int c = w*32 + ms*16 + q*4 + r;
                    outC[((long long)b*128 + c)*HW + p] = (unsigned short)o4[r];
                }
            }
            if (outF){
                #pragma unroll
                for (int r = 0; r < 4; r++){
                    int c = w*32 + ms*16 + q*4 + r;
                    outF[((long long)b*128 + c)*HW + p] = vals[r];
                }
            }
        }
    }
}

// ---------------- attention pass 1 (split-j, 128 k-rows/block, no-max softmax) ----------------
__global__ __launch_bounds__(256)
void k_attn_stats3(const unsigned short* __restrict__ QT,
                   const unsigned short* __restrict__ PT,
                   float* __restrict__ lpart){
    int b = blockIdx.z, jc = blockIdx.y, k0 = blockIdx.x * 128;
    const unsigned short* QTb = QT + (long long)b * HW * CO;
    const unsigned short* PTb = PT + (long long)b * HW * CO;
    __shared__ unsigned short Ps[2][64][132];
    int t = threadIdx.x;
    int w = t >> 6, lane = t & 63, m = lane & 15, q = lane >> 4;
    s8v a[2][4];
    #pragma unroll
    for (int kh = 0; kh < 2; kh++)
        #pragma unroll
        for (int ks = 0; ks < 4; ks++)
            a[kh][ks] = *(const s8v*)(QTb + (long long)(k0 + kh*64 + w*16 + m) * CO + q*8 + ks*32);
    float rl[2][4];
    #pragma unroll
    for (int kh = 0; kh < 2; kh++)
        #pragma unroll
        for (int r = 0; r < 4; r++) rl[kh][r] = 0.f;
    const float scale = 0.015625f;           // 1/sqrt(4096)
    int jbase = jc * 1024;
    int sr = t >> 2, sch = t & 3;
    uint4 pf[4];
    {   const uint4* src = (const uint4*)(PTb + (long long)(jbase + sr) * CO + sch * 32);
        #pragma unroll
        for (int i = 0; i < 4; i++) pf[i] = src[i];
    }
    for (int jt = 0; jt < 16; jt++){
        int cur = jt & 1;
        {   uint4* dst = (uint4*)&Ps[cur][sr][sch * 32];
            #pragma unroll
            for (int i = 0; i < 4; i++) dst[i] = pf[i];
        }
        __syncthreads();
        if (jt < 15){
            const uint4* src = (const uint4*)(PTb + (long long)(jbase + (jt+1)*64 + sr) * CO + sch * 32);
            #pragma unroll
            for (int i = 0; i < 4; i++) pf[i] = src[i];
        }
        #pragma unroll
        for (int kh = 0; kh < 2; kh++){
            float sv[4][4];
            #pragma unroll
            for (int ct = 0; ct < 4; ct++){
                f4v acc = {0.f,0.f,0.f,0.f};
                #pragma unroll
                for (int ks = 0; ks < 4; ks++){
                    s8v bv = *(const s8v*)&Ps[cur][ct*16 + m][q*8 + ks*32];
                    acc = __builtin_amdgcn_mfma_f32_16x16x32_bf16(a[kh][ks], bv, acc, 0, 0, 0);
                }
                #pragma unroll
                for (int r = 0; r < 4; r++) sv[ct][r] = acc[r] * scale;
            }
            #pragma unroll
            for (int r = 0; r < 4; r++){
                float se = __expf(sv[0][r]) + __expf(sv[1][r])
                         + __expf(sv[2][r]) + __expf(sv[3][r]);
                #pragma unroll
                for (int msk = 1; msk < 16; msk <<= 1) se += __shfl_xor(se, msk);
                rl[kh][r] += se;
            }
        }
    }
    if (m == 0){
        #pragma unroll
        for (int kh = 0; kh < 2; kh++)
            #pragma unroll
            for (int r = 0; r < 4; r++){
                int k = k0 + kh*64 + w*16 + q*4 + r;
                lpart[(long long)jc * (NB*HW) + (long long)b*HW + k] = rl[kh][r];
            }
    }
}

// ---------------- attention pass 2 (split-k x2): wave-private DMA pipeline, counted vmcnt ----------------
__global__ __launch_bounds__(256)
void k_attn_apply2(const unsigned short* __restrict__ QT,
                   const unsigned short* __restrict__ PT,
                   const unsigned short* __restrict__ Pb,
                   const float* __restrict__ lpart,
                   float* __restrict__ Lp){
    int b = blockIdx.z, kc = blockIdx.y, j0 = blockIdx.x * 64;
    const unsigned short* QTb = QT + (long long)b * HW * CO;
    const unsigned short* PTb = PT + (long long)b * HW * CO;
    const unsigned short* Pbb = Pb + (long long)b * CO * HW;
    __shared__ __align__(16) unsigned short Qks[64*128];  // 16 KB
    __shared__ __align__(16) unsigned short Pcs[128*64];  // 16 KB
    __shared__ unsigned short Et[64][72];
    __shared__ float Il[2048];
    int t = threadIdx.x;
    int w = t >> 6, lane = t & 63, m = lane & 15, q = lane >> 4;
    int kbase = kc * 2048;
    int rl4 = lane >> 4;                                  // Qks DMA: row within 4-row group
    int rl8 = lane >> 3;                                  // Pcs DMA: row within 8-row group
    int gch8 = (lane & 7) ^ rl8;                          // Pcs source chunk
    {   // fused stat combine (plain sum, no-max): Il for this block's k-range
        #pragma unroll
        for (int r = 0; r < 8; r++){
            int kl = t*8 + r;
            long long gi = (long long)b*HW + kbase + kl;
            float l = lpart[gi] + lpart[gi+16384] + lpart[gi+32768] + lpart[gi+49152];
            Il[kl] = 1.f / l;
        }
    }
    {   // stage PT j-tile into Qks (4 issues/wave) then Pcs(kt=0) (4 issues/wave)
        #pragma unroll
        for (int i = 0; i < 4; i++){
            int rowb = w*16 + i*4;
            int gch = (lane & 15) ^ ((rowb & 15) + rl4);
            lds_dma16(PTb + (long long)(j0 + rowb + rl4)*CO + gch*8, &Qks[rowb*128]);
        }
        #pragma unroll
        for (int i = 0; i < 4; i++){
            int rowb = w*32 + i*8;
            lds_dma16(Pbb + (long long)(rowb + rl8)*HW + kbase + gch8*8, &Pcs[rowb*64]);
        }
    }
    asm volatile("s_waitcnt vmcnt(4) lgkmcnt(0)" ::: "memory");  // PT done; Il written; Pcs(0) in flight
    __builtin_amdgcn_s_barrier();                                // publish PT + Il
    __builtin_amdgcn_sched_barrier(0);
    s8v bj[4][4];
    #pragma unroll
    for (int ct = 0; ct < 4; ct++)
        #pragma unroll
        for (int ks = 0; ks < 4; ks++)
            bj[ct][ks] = *(const s8v*)&Qks[(ct*16 + m)*128 + ((q + 4*ks) ^ m)*8];
    asm volatile("s_waitcnt lgkmcnt(0)" ::: "memory");           // bj in regs
    __builtin_amdgcn_s_barrier();                                // all waves done reading PT tile
    __builtin_amdgcn_sched_barrier(0);
    {   // Qks <- QT k-tile for kt=0
        #pragma unroll
        for (int i = 0; i < 4; i++){
            int rowb = w*16 + i*4;
            int gch = (lane & 15) ^ ((rowb & 15) + rl4);
            lds_dma16(QTb + (long long)(kbase + rowb + rl4)*CO + gch*8, &Qks[rowb*128]);
        }
    }
    f4v accL[2][4];
    #pragma unroll
    for (int mt = 0; mt < 2; mt++)
        #pragma unroll
        for (int ct = 0; ct < 4; ct++){ f4v z = {0.f,0.f,0.f,0.f}; accL[mt][ct] = z; }
    const float scale = 0.015625f;
    for (int kt = 0; kt < 32; kt++){
        int k0 = kbase + kt*64;
        // wait this wave's Qks(kt) (oldest); Pcs stays in flight (kt=0: queue order differs -> drain)
        if (kt == 0) asm volatile("s_waitcnt vmcnt(0)" ::: "memory");
        else         asm volatile("s_waitcnt vmcnt(4)" ::: "memory");
        __builtin_amdgcn_sched_barrier(0);
        // ---- QK phase (own Qks rows) ----
        s8v aS[4];
        #pragma unroll
        for (int ks = 0; ks < 4; ks++)
            aS[ks] = *(const s8v*)&Qks[(w*16 + m)*128 + ((q + 4*ks) ^ m)*8];
        float il[4];
        #pragma unroll
        for (int r = 0; r < 4; r++) il[r] = Il[kt*64 + w*16 + q*4 + r];
        #pragma unroll
        for (int ct = 0; ct < 4; ct++){
            f4v s = {0.f,0.f,0.f,0.f};
            #pragma unroll
            for (int ks = 0; ks < 4; ks++)
                s = __builtin_amdgcn_mfma_f32_16x16x32_bf16(aS[ks], bj[ct][ks], s, 0, 0, 0);
            s4v e4;
            #pragma unroll
            for (int r = 0; r < 4; r++)
                e4[r] = (short)f2bf(__expf(s[r]*scale) * il[r]);
            *(s4v*)&Et[ct*16 + m][w*16 + q*4] = e4;
        }
        // prefetch own Qks rows for kt+1 (aS consumed via MFMA lgkm waits)
        if (kt+1 < 32){
            #pragma unroll
            for (int i = 0; i < 4; i++){
                int rowb = w*16 + i*4;
                int gch = (lane & 15) ^ ((rowb & 15) + rl4);
                lds_dma16(QTb + (long long)(k0 + 64 + rowb + rl4)*CO + gch*8, &Qks[rowb*128]);
            }
        }
        asm volatile("s_waitcnt lgkmcnt(0)" ::: "memory");   // Et committed
        __builtin_amdgcn_s_barrier();                        // publish Et (DMAs stay in flight)
        __builtin_amdgcn_sched_barrier(0);
        // wait this wave's Pcs(kt) (oldest); Qks(kt+1) stays in flight
        asm volatile("s_waitcnt vmcnt(4)" ::: "memory");
        __builtin_amdgcn_sched_barrier(0);
        // ---- PV phase (own Pcs rows, shared Et) ----
        s8v aP[2][2];
        #pragma unroll
        for (int mt = 0; mt < 2; mt++)
            #pragma unroll
            for (int ks2 = 0; ks2 < 2; ks2++)
                aP[mt][ks2] = *(const s8v*)&Pcs[(w*32 + mt*16 + m)*64 + ((q + 4*ks2) ^ (m&7))*8];
        #pragma unroll
        for (int ct = 0; ct < 4; ct++){
            s8v bE0 = *(const s8v*)&Et[ct*16 + m][q*8];
            s8v bE1 = *(const s8v*)&Et[ct*16 + m][q*8 + 32];
            #pragma unroll
            for (int mt = 0; mt < 2; mt++){
                accL[mt][ct] = __builtin_amdgcn_mfma_f32_16x16x32_bf16(aP[mt][0], bE0, accL[mt][ct], 0, 0, 0);
                accL[mt][ct] = __builtin_amdgcn_mfma_f32_16x16x32_bf16(aP[mt][1], bE1, accL[mt][ct], 0, 0, 0);
            }
        }
        // prefetch own Pcs rows for kt+1 (aP consumed)
        if (kt+1 < 32){
            #pragma unroll
            for (int i = 0; i < 4; i++){
                int rowb = w*32 + i*8;
                lds_dma16(Pbb + (long long)(rowb + rl8)*HW + k0 + 64 + gch8*8, &Pcs[rowb*64]);
            }
        }
        __builtin_amdgcn_s_barrier();                        // Et(kt) reads done before Et(kt+1) writes
        __builtin_amdgcn_sched_barrier(0);
    }
    float* Lpb = Lp + ((long long)(kc*NB + b) * CO) * HW;
    #pragma unroll
    for (int mt = 0; mt < 2; mt++)
        #pragma unroll
        for (int ct = 0; ct < 4; ct++)
            #pragma unroll
            for (int r = 0; r < 4; r++){
                int c = w*32 + mt*16 + q*4 + r;
                Lpb[(long long)c*HW + j0 + ct*16 + m] = accL[mt][ct][r];
            }
}

// ---------------- fused: O = xa + sum(Lp) -> bf16 B-tile -> conv2 -> out f32 (DMA A-staging) ----------------
__global__ __launch_bounds__(256)
void k_outfused(const unsigned short* __restrict__ A,    // w_c2 [256][128] bf16
                const float* __restrict__ Lp, const float* __restrict__ xa,
                const float* __restrict__ bias, float* __restrict__ out){
    int b = blockIdx.y, j0 = blockIdx.x*32;
    __shared__ unsigned short Bs[32][136];
    __shared__ __align__(16) char pool[256*68*2];   // phase1: Bsf[128][33] f32; phase2: As[256*64] bf16
    int t = threadIdx.x;
    // phase 1: O tile f32 = xa + 2 partials (coalesced c-rows)
    {
        float* Bsf = (float*)pool;
        int c = t>>1, jh = t&1;
        long long base = ((long long)b*CO + c)*HW + j0 + jh*16;
        const long long csz = (long long)NB*CO*HW;
        float v[16];
        #pragma unroll
        for (int r = 0; r < 16; r++) v[r] = xa[base + r];
        #pragma unroll
        for (int pidx = 0; pidx < 2; pidx++){
            const float* src = Lp + pidx*csz + base;
            #pragma unroll
            for (int r = 0; r < 16; r++) v[r] += src[r];
        }
        #pragma unroll
        for (int r = 0; r < 16; r++) Bsf[c*33 + jh*16 + r] = v[r];
    }
    __syncthreads();
    // transpose to bf16 B-tile [j][c]
    {
        const float* Bsf = (const float*)pool;
        int j = t>>3, cs = t&7;
        #pragma unroll
        for (int r = 0; r < 16; r++){
            int c = cs*16 + r;
            Bs[j][c] = f2bf(Bsf[c*33 + j]);
        }
    }
    __syncthreads();
    // phase 2: GEMM M=256 x N=32 x K=128, A staged via DMA (pitch 64, swizzled)
    unsigned short* As = (unsigned short*)pool;
    int w = t>>6, lane = t&63, m = lane&15, q = lane>>4;
    int rl8 = lane>>3, gch = (lane&7) ^ rl8, rsw = m&7;
    f4v acc[4][2];
    #pragma unroll
    for (int ms = 0; ms < 4; ms++)
        #pragma unroll
        for (int ct = 0; ct < 2; ct++){ f4v z = {0.f,0.f,0.f,0.f}; acc[ms][ct] = z; }
    for (int k0 = 0; k0 < 128; k0 += 64){
        __syncthreads();                                  // prior reads of pool/As done
        #pragma unroll
        for (int i = 0; i < 8; i++){
            int ar = w*64 + i*8;
            lds_dma16(A + (long long)(ar + rl8)*128 + k0 + gch*8, &As[ar*64]);
        }
        __syncthreads();                                  // vmcnt(0) drained -> visible
        #pragma unroll
        for (int ks = 0; ks < 2; ks++){
            s8v bfr[2];
            #pragma unroll
            for (int ct = 0; ct < 2; ct++) bfr[ct] = *(const s8v*)&Bs[ct*16+m][k0 + ks*32 + q*8];
            #pragma unroll
            for (int ms = 0; ms < 4; ms++){
                s8v afr = *(const s8v*)&As[(w*64 + ms*16 + m)*64 + ((q + 4*ks) ^ rsw)*8];
                #pragma unroll
                for (int ct = 0; ct < 2; ct++)
                    acc[ms][ct] = __builtin_amdgcn_mfma_f32_16x16x32_bf16(afr, bfr[ct], acc[ms][ct], 0,0,0);
            }
        }
    }
    #pragma unroll
    for (int ct = 0; ct < 2; ct++){
        int p = j0 + ct*16 + m;
        #pragma unroll
        for (int ms = 0; ms < 4; ms++)
            #pragma unroll
            for (int r = 0; r < 4; r++){
                int c = w*64 + ms*16 + q*4 + r;
                out[((long long)b*256 + c)*HW + p] = acc[ms][ct][r] + bias[c];
            }
    }
}

extern "C" void kernel_launch(void* const* d_in, const int* in_sizes, int n_in,
                              void* d_out, int out_size, void* d_ws, size_t ws_size,
                              hipStream_t stream) {
    const float* x       = (const float*)d_in[0];
    const float* conv1_w = (const float*)d_in[1];
    const float* conv1_b = (const float*)d_in[2];
    const float* conv2_w = (const float*)d_in[3];
    const float* conv2_b = (const float*)d_in[4];
    const float* cw_w1   = (const float*)d_in[5];
    const float* cw_b1   = (const float*)d_in[6];
    const float* cw_g    = (const float*)d_in[7];
    const float* cw_bt   = (const float*)d_in[8];
    const float* cw_w2   = (const float*)d_in[9];
    const float* cw_b2   = (const float*)d_in[10];
    const float* a0_w    = (const float*)d_in[11];
    const float* a0_g    = (const float*)d_in[12];
    const float* a0_b    = (const float*)d_in[13];
    const float* a1_w    = (const float*)d_in[14];
    const float* a1_g    = (const float*)d_in[15];
    const float* a1_b    = (const float*)d_in[16];
    const float* a2_w    = (const float*)d_in[17];
    const float* a2_g    = (const float*)d_in[18];
    const float* a2_b    = (const float*)d_in[19];
    const float* a3_w    = (const float*)d_in[20];
    const float* a3_g    = (const float*)d_in[21];
    const float* a3_b    = (const float*)d_in[22];
    const float* ap_w    = (const float*)d_in[23];
    const float* ap_g    = (const float*)d_in[24];
    const float* ap_b    = (const float*)d_in[25];
    const float* pj_w    = (const float*)d_in[26];
    const float* pj_g    = (const float*)d_in[27];
    const float* pj_b    = (const float*)d_in[28];
    float* out = (float*)d_out;

    // ---- workspace layout ----
    float* ws    = (float*)d_ws;
    float* avg   = ws;                  // 1024
    float* mx    = ws + 1024;           // 1024
    float* sv    = ws + 2048;           // 1024
    float* gp    = ws + 3072;           // 1024
    float* zbuf  = ws + 4096;           // 256 f32 zero-page for OOB DMA
    float* xa    = ws + 37888;          // 2,097,152
    float* lpart = xa + 2097152;        // 65536
    unsigned short* sb = (unsigned short*)(ws + 4232192);
    unsigned short* xT    = sb;                    // 4,194,304
    unsigned short* xcT   = sb + 4194304;          // 4,194,304
    unsigned short* catT  = sb + 8388608;          // 20,971,520
    unsigned short* projT = sb + 29360128;         // 4,194,304
    unsigned short* P_bf  = sb + 33554432;         // 2,097,152
    unsigned short* PT_bf = sb + 35651584;         // 2,097,152
    unsigned short* QT_bf = sb + 37748736;         // 2,097,152
    unsigned short* w_c1  = sb + 41943040;         // 32768
    unsigned short* w_a0  = sb + 41975808;         // 65536
    unsigned short* w_pj  = sb + 42041344;         // 327680
    unsigned short* w_c2  = sb + 42369024;         // 32768
    unsigned short* w_d3  = sb + 42401792;         // 589824
    unsigned short* w_d6  = sb + 42991616;         // 589824
    unsigned short* w_d9  = sb + 43581440;         // 589824
    float* Lp = (float*)catT;           // alias: catT dead after proj (16.8MB in 42MB region)

    // ---- rowstats + all weight casts (one launch) ----
    k_pre<<<dim3(9728), 256, 0, stream>>>(x, avg, mx,
                                          conv1_w, a0_w, pj_w, conv2_w, a1_w, a2_w, a3_w,
                                          w_c1, w_a0, w_pj, w_c2, w_d3, w_d6, w_d9);
    k_cw<<<dim3(NB), 256, 0, stream>>>(avg, mx, cw_w1, cw_b1, cw_g, cw_bt, cw_w2, cw_b2, sv, gp, zbuf);

    // ---- x -> xT bf16 and xcT ----
    k_xT<<<dim3(64, 4, NB), 256, 0, stream>>>(x, sv, xT, xcT);

    // ---- x1 = conv1(x)+b -> P_bf/PT_bf ----
    k_conv1m<<<dim3(128, NB), 256, 0, stream>>>(w_c1, xT, conv1_b, PT_bf, P_bf, nullptr);

    // ---- ASPP: a0 + 3 dilated convs + pool/bcast in ONE launch (N=128, DMA staging) ----
    k_aspp<<<dim3(32, 5, NB), 512, 0, stream>>>(w_a0, w_d3, w_d6, w_d9, xcT,
                                                a0_g, a0_b, a1_g, a1_b, a2_g, a2_b, a3_g, a3_b,
                                                gp, ap_w, ap_g, ap_b, zbuf, catT);

    // ---- proj = GELU(LN(conv1x1(cat))) -> projT bf16 (pipelined dbuf DMA) ----
    k_branch1<<<dim3(128, NB), 512, 0, stream>>>(w_pj, 1280, catT, pj_g, pj_b, projT, 256, 0);

    // ---- xa = conv1(proj)+b -> xa f32 + QT_bf ----
    k_conv1m<<<dim3(128, NB), 256, 0, stream>>>(w_c1, projT, conv1_b, QT_bf, nullptr, xa);

    // ---- attention (no-max softmax; comb fused into apply; kc-split = 2; counted-vmcnt apply) ----
    k_attn_stats3<<<dim3(32, 4, NB), 256, 0, stream>>>(QT_bf, PT_bf, lpart);
    k_attn_apply2<<<dim3(64, 2, NB), 256, 0, stream>>>(QT_bf, PT_bf, P_bf, lpart, Lp);

    // ---- out = conv2(xa + sum Lp) + b (fused) ----
    k_outfused<<<dim3(128, NB), 256, 0, stream>>>(w_c2, Lp, xa, conv2_b, out);

    (void)in_sizes; (void)n_in; (void)out_size; (void)ws_size;
}

// Round 11
// 361.639 us; speedup vs baseline: 1.0957x; 1.0285x over previous
//
#include <hip/hip_runtime.h>
#include <hip/hip_bf16.h>
#include <math.h>

// Problem constants (B=4, Cin=256, Cout=128, H=W=64)
#define NB 4
#define CI 256
#define CO 128
#define HW 4096

typedef __attribute__((ext_vector_type(8))) short s8v;   // 8 bf16 = 4 VGPRs (MFMA A/B frag)
typedef __attribute__((ext_vector_type(4))) short s4v;
typedef __attribute__((ext_vector_type(4))) float f4v;   // MFMA C/D frag

__device__ __forceinline__ unsigned short f2bf(float f){
    __hip_bfloat16 h = __float2bfloat16(f);   // RNE
    return *reinterpret_cast<unsigned short*>(&h);
}

// async global->LDS DMA, 16B per lane; LDS dest = wave-uniform base + lane*16
__device__ __forceinline__ void lds_dma16(const void* g, void* l){
    __builtin_amdgcn_global_load_lds((const __attribute__((address_space(1))) unsigned int*)g,
                                     (__attribute__((address_space(3))) unsigned int*)l,
                                     16, 0, 0);
}

// A&S 7.1.26 erf (max abs err 1.5e-7)
__device__ __forceinline__ float gelu_f(float x){
    float z  = x * 0.70710678118654752f;
    float az = fabsf(z);
    float tt = 1.f / (1.f + 0.3275911f * az);
    float poly = tt*(0.254829592f + tt*(-0.284496736f + tt*(1.421413741f +
                 tt*(-1.453152027f + tt*1.061405429f))));
    float erfv = 1.f - poly * __expf(-az*az);
    erfv = (z < 0.f) ? -erfv : erfv;
    return 0.5f * x * (1.f + erfv);
}

// ---------------- fused: per-channel avg/max (blocks 0..1023) + ALL weight casts ----------------
__global__ void k_pre(const float* __restrict__ x, float* __restrict__ avg, float* __restrict__ mx,
                      const float* __restrict__ c1, const float* __restrict__ a0,
                      const float* __restrict__ pj, const float* __restrict__ c2,
                      const float* __restrict__ d3, const float* __restrict__ d6,
                      const float* __restrict__ d9,
                      unsigned short* __restrict__ w_c1, unsigned short* __restrict__ w_a0,
                      unsigned short* __restrict__ w_pj, unsigned short* __restrict__ w_c2,
                      unsigned short* __restrict__ w_d3, unsigned short* __restrict__ w_d6,
                      unsigned short* __restrict__ w_d9){
    int blk = blockIdx.x;
    int t = threadIdx.x;
    if (blk < 1024){
        const float* p = x + (long long)blk * HW;
        float s = 0.f, m = -1e30f;
        for (int i = t; i < HW; i += 256){ float v = p[i]; s += v; m = fmaxf(m, v); }
        __shared__ float ss[256], sm[256];
        ss[t] = s; sm[t] = m; __syncthreads();
        for (int o = 128; o > 0; o >>= 1){
            if (t < o){ ss[t] += ss[t+o]; sm[t] = fmaxf(sm[t], sm[t+o]); }
            __syncthreads();
        }
        if (t == 0){ avg[blk] = ss[0] / (float)HW; mx[blk] = sm[0]; }
        return;
    }
    int i = (blk - 1024)*256 + t;
    if (i < 458752){
        if (i < 32768)        w_c1[i]        = f2bf(c1[i]);
        else if (i < 98304)   w_a0[i-32768]  = f2bf(a0[i-32768]);
        else if (i < 425984)  w_pj[i-98304]  = f2bf(pj[i-98304]);
        else                  w_c2[i-425984] = f2bf(c2[i-425984]);
    } else {
        int j = i - 458752;
        int which = j / 589824;
        int l = j - which*589824;
        int tap = l >> 16, rem = l & 65535, o = rem >> 8, ci = rem & 255;
        const float* src = (which==0) ? d3 : ((which==1) ? d6 : d9);
        unsigned short* dst = (which==0) ? w_d3 : ((which==1) ? w_d6 : w_d9);
        dst[l] = f2bf(src[o*2304 + ci*9 + tap]);
    }
}

// ---------------- ChannelWeighting; also gp = avg*(1+s); block 0 zeroes the DMA zero-page ----------------
__global__ void k_cw(const float* __restrict__ avg, const float* __restrict__ mx,
                     const float* __restrict__ w1, const float* __restrict__ b1,
                     const float* __restrict__ lng, const float* __restrict__ lnb,
                     const float* __restrict__ w2, const float* __restrict__ b2,
                     float* __restrict__ sv, float* __restrict__ gp,
                     float* __restrict__ zb){
    int b = blockIdx.x, t = threadIdx.x;
    if (b == 0) zb[t] = 0.f;                 // 1 KB zero-page for OOB DMA lanes
    __shared__ float o_s[256];
    __shared__ float h_s[128];
    __shared__ float stat[2];
    float a = avg[b*256 + t];
    o_s[t] = fabsf(a - mx[b*256 + t]) * a;
    __syncthreads();
    if (t < 128){
        float h = b1[t];
        for (int i = 0; i < 256; i++) h += o_s[i] * w1[t*256 + i];
        h_s[t] = h;
    }
    __syncthreads();
    if (t == 0){
        float s = 0.f, s2 = 0.f;
        for (int j = 0; j < 128; j++){ s += h_s[j]; s2 += h_s[j]*h_s[j]; }
        float mean = s / 128.f;
        float var  = s2 / 128.f - mean*mean;
        stat[0] = mean; stat[1] = rsqrtf(var + 1e-5f);
    }
    __syncthreads();
    if (t < 128) h_s[t] = lng[t] * ((h_s[t] - stat[0]) * stat[1]) + lnb[t];
    __syncthreads();
    float z = b2[t];
    for (int j = 0; j < 128; j++) z += h_s[j] * w2[t*128 + j];
    float sig = 1.f / (1.f + __expf(-z));
    sv[b*256 + t] = sig;
    gp[b*256 + t] = a * (1.f + sig);
}

// ---------------- x -> xT bf16 [b][HW][256] and xcT = bf16(x*(1+s)) ----------------
__global__ void k_xT(const float* __restrict__ x, const float* __restrict__ sv,
                     unsigned short* __restrict__ xT, unsigned short* __restrict__ xcT){
    int b = blockIdx.z, c0 = blockIdx.y*64, h0 = blockIdx.x*64;
    __shared__ unsigned short T1[64][66], T2[64][66];
    int t = threadIdx.x;
    int hl = t & 63, cs = t >> 6;
    #pragma unroll
    for (int r = 0; r < 16; r++){
        int c = cs*16 + r;
        float v = x[((long long)b*256 + c0 + c)*HW + h0 + hl];
        float sc = 1.f + sv[b*256 + c0 + c];
        T1[c][hl] = f2bf(v);
        T2[c][hl] = f2bf(v*sc);
    }
    __syncthreads();
    int cl = t & 63, hs = t >> 6;
    #pragma unroll
    for (int r = 0; r < 16; r++){
        int h = hs*16 + r;
        long long o = ((long long)b*HW + h0 + h)*256 + c0 + cl;
        xT[o]  = T1[cl][h];
        xcT[o] = T2[cl][h];
    }
}

// ============ 8-wave epilogue, N=32: LN(256ch)+GELU -> transposed bf16 ============
__device__ __forceinline__ void ln_epi32(f4v acc[2][2],
        int b, int n0, int w, int lane, int m, int q, int t,
        const float* Gs, const float* Bts,
        float (*Psum)[32], float (*Psq)[32], float* Mn, float* Iv,
        unsigned short* __restrict__ outT, int outPitch, int colOff){
    float ls[2], ls2[2];
    #pragma unroll
    for (int ct = 0; ct < 2; ct++){
        float s = 0.f, s2 = 0.f;
        #pragma unroll
        for (int ms = 0; ms < 2; ms++)
            #pragma unroll
            for (int r = 0; r < 4; r++){ float v = acc[ms][ct][r]; s += v; s2 += v*v; }
        ls[ct] = s; ls2[ct] = s2;
    }
    #pragma unroll
    for (int ct = 0; ct < 2; ct++){
        ls[ct]  += __shfl_xor(ls[ct], 16);  ls[ct]  += __shfl_xor(ls[ct], 32);
        ls2[ct] += __shfl_xor(ls2[ct], 16); ls2[ct] += __shfl_xor(ls2[ct], 32);
    }
    if (lane < 16){
        #pragma unroll
        for (int ct = 0; ct < 2; ct++){ Psum[w][ct*16+lane] = ls[ct]; Psq[w][ct*16+lane] = ls2[ct]; }
    }
    __syncthreads();
    if (t < 32){
        float s = 0.f, s2 = 0.f;
        #pragma unroll
        for (int ww = 0; ww < 8; ww++){ s += Psum[ww][t]; s2 += Psq[ww][t]; }
        float mean = s * (1.f/256.f);
        Mn[t] = mean;
        Iv[t] = rsqrtf(s2*(1.f/256.f) - mean*mean + 1e-6f);
    }
    __syncthreads();
    #pragma unroll
    for (int ct = 0; ct < 2; ct++){
        int p = ct*16 + m;
        float mean = Mn[p], inv = Iv[p];
        long long rowb = ((long long)b*HW + n0 + p)*outPitch + colOff;
        #pragma unroll
        for (int ms = 0; ms < 2; ms++){
            s4v o4;
            #pragma unroll
            for (int r = 0; r < 4; r++){
                int c = w*32 + ms*16 + q*4 + r;
                float h = Gs[c]*((acc[ms][ct][r] - mean)*inv) + Bts[c];
                o4[r] = (short)f2bf(gelu_f(h));
            }
            *(s4v*)(outT + rowb + w*32 + ms*16 + q*4) = o4;
        }
    }
}

// ---------------- unified ASPP v3 (round-2/6 proven): N=128, global_load_lds staging, swizzled read ----------------
__global__ __launch_bounds__(512, 4)
void k_aspp(const unsigned short* __restrict__ w_a0, const unsigned short* __restrict__ w_d3,
            const unsigned short* __restrict__ w_d6, const unsigned short* __restrict__ w_d9,
            const unsigned short* __restrict__ BT,
            const float* __restrict__ a0_g, const float* __restrict__ a0_b,
            const float* __restrict__ a1_g, const float* __restrict__ a1_b,
            const float* __restrict__ a2_g, const float* __restrict__ a2_b,
            const float* __restrict__ a3_g, const float* __restrict__ a3_b,
            const float* __restrict__ gp, const float* __restrict__ ap_w,
            const float* __restrict__ ap_g, const float* __restrict__ ap_b,
            const float* __restrict__ zbuf,
            unsigned short* __restrict__ catT){
    int br = blockIdx.y, b = blockIdx.z;
    int t = threadIdx.x;
    __shared__ __align__(16) unsigned short As[256*64];   // 32 KB, pitch 64 shorts (128 B)
    __shared__ __align__(16) unsigned short Bs[128*64];   // 16 KB (epilogue stats aliased here)
    __shared__ float Gs[256], Bts[256];
    if (br == 4){
        // ---- pool + broadcast ----
        int p0 = blockIdx.x*128;
        float* z_s = (float*)As;                          // 256 f32
        unsigned short* bp_s = As + 2048;                 // 256 bf16
        float* stat = (float*)(As + 4096);
        if (t < 256){
            float z = 0.f;
            for (int c = 0; c < 256; c++) z += gp[b*256 + c] * ap_w[t*256 + c];
            z_s[t] = z;
        }
        __syncthreads();
        if (t == 0){
            float s = 0.f, s2 = 0.f;
            for (int c = 0; c < 256; c++){ s += z_s[c]; s2 += z_s[c]*z_s[c]; }
            float mean = s / 256.f, var = s2 / 256.f - mean*mean;
            stat[0] = mean; stat[1] = rsqrtf(var + 1e-6f);
        }
        __syncthreads();
        if (t < 256){
            float h = ap_g[t] * ((z_s[t] - stat[0]) * stat[1]) + ap_b[t];
            bp_s[t] = f2bf(gelu_f(h));
        }
        __syncthreads();
        for (int it = 0; it < 8; it++){
            int i = it*512 + t;
            int pl = i >> 5, cj = (i & 31) * 8;
            s8v v8;
            #pragma unroll
            for (int k2 = 0; k2 < 8; k2++) v8[k2] = (short)bp_s[cj + k2];
            *(s8v*)(catT + ((long long)b*HW + p0 + pl)*1280 + 1024 + cj) = v8;
        }
        return;
    }
    // ---- conv branches (br0 = 1-tap case: tap=0, d=0) ----
    int n0 = blockIdx.x * 128;
    const unsigned short* BTb = BT + (long long)b*HW*256;
    const unsigned short* A  = (br==0) ? w_a0 : (br==1) ? w_d3 : (br==2) ? w_d6 : w_d9;
    const float* g   = (br==0) ? a0_g : (br==1) ? a1_g : (br==2) ? a2_g : a3_g;
    const float* bta = (br==0) ? a0_b : (br==1) ? a1_b : (br==2) ? a2_b : a3_b;
    int d    = (br==0) ? 0 : (br==1) ? 3 : (br==2) ? 6 : 9;
    int NS   = (br==0) ? 4 : 36;                          // (tap,kc) stages, kc fastest
    if (t < 256){ Gs[t] = g[t]; Bts[t] = bta[t]; }

    int w = t>>6, lane = t&63, m = lane&15, q = lane>>4;
    int wr = w>>1, wc = w&1;                              // wave tile: rows wr*64.., cols wc*64..
    int rsw = m&7;                                        // read-side swizzle key
    int rl8 = lane>>3;                                    // lane's row within an 8-row DMA group
    int gch = (lane&7) ^ rl8;                             // pre-swizzled source chunk
    int aoff = rl8*256 + gch*8;                           // per-lane A source offset (shorts)
    int y0 = n0 >> 6;                                     // image row of first tile position

    f4v acc[4][4];
    #pragma unroll
    for (int ms = 0; ms < 4; ms++)
        #pragma unroll
        for (int ct = 0; ct < 4; ct++){ f4v z = {0.f,0.f,0.f,0.f}; acc[ms][ct] = z; }

    for (int s = 0; s < NS; ++s){
        int tap = s>>2, kc = s&3;
        int dy = tap/3 - 1, dx = tap%3 - 1;
        // ---- A: 256 rows x 64 ch; wave w stages rows w*32..w*32+31 (4 DMA issues) ----
        const unsigned short* abase = A + tap*65536 + kc*64 + aoff;
        #pragma unroll
        for (int i = 0; i < 4; i++){
            int row0 = w*32 + i*8;
            lds_dma16(abase + row0*256, &As[row0*64]);
        }
        // ---- B: 128 positions x 64 ch; wave w stages rows w*16..w*16+15 (2 DMA issues) ----
        int xadd = rl8 + dx*d;
        #pragma unroll
        for (int i = 0; i < 2; i++){
            int bn0 = w*16 + i*8;
            int yy = y0 + (bn0>>6) + dy*d;
            int xs = (bn0 & 63) + xadd;
            const unsigned short* gsrc = ((unsigned)yy < 64u && (unsigned)xs < 64u)
                ? (BTb + (long long)(yy*64 + xs)*256 + kc*64 + gch*8)
                : (const unsigned short*)zbuf;
            lds_dma16(gsrc, &Bs[bn0*64]);
        }
        __syncthreads();                                  // vmcnt(0) drained here -> data visible
        #pragma unroll
        for (int ks = 0; ks < 2; ks++){
            s8v bfr[4];
            #pragma unroll
            for (int ct = 0; ct < 4; ct++)
                bfr[ct] = *(const s8v*)&Bs[(wc*64 + ct*16 + m)*64 + ((q + 4*ks) ^ rsw)*8];
            #pragma unroll
            for (int ms = 0; ms < 4; ms++){
                s8v afr = *(const s8v*)&As[(wr*64 + ms*16 + m)*64 + ((q + 4*ks) ^ rsw)*8];
                #pragma unroll
                for (int ct = 0; ct < 4; ct++)
                    acc[ms][ct] = __builtin_amdgcn_mfma_f32_16x16x32_bf16(afr, bfr[ct], acc[ms][ct], 0,0,0);
            }
        }
        __syncthreads();                                  // all LDS reads done before next DMA
    }
    // ---- epilogue: LN over 256 channels per position (128 positions), GELU, store ----
    float* Psum = (float*)Bs;                             // [4][128]
    float* Psq  = Psum + 512;                             // [4][128]
    float* Mn   = Psq  + 512;                             // [128]
    float* Iv   = Mn   + 128;                             // [128]
    #pragma unroll
    for (int ct = 0; ct < 4; ct++){
        float s = 0.f, s2 = 0.f;
        #pragma unroll
        for (int ms = 0; ms < 4; ms++)
            #pragma unroll
            for (int r = 0; r < 4; r++){ float v = acc[ms][ct][r]; s += v; s2 += v*v; }
        s  += __shfl_xor(s, 16);  s  += __shfl_xor(s, 32);
        s2 += __shfl_xor(s2, 16); s2 += __shfl_xor(s2, 32);
        if (lane < 16){
            Psum[wr*128 + wc*64 + ct*16 + lane] = s;
            Psq [wr*128 + wc*64 + ct*16 + lane] = s2;
        }
    }
    __syncthreads();
    if (t < 128){
        float s  = Psum[t] + Psum[128+t] + Psum[256+t] + Psum[384+t];
        float s2 = Psq [t] + Psq [128+t] + Psq [256+t] + Psq [384+t];
        float mean = s * (1.f/256.f);
        Mn[t] = mean;
        Iv[t] = rsqrtf(s2*(1.f/256.f) - mean*mean + 1e-6f);
    }
    __syncthreads();
    #pragma unroll
    for (int ct = 0; ct < 4; ct++){
        int p = wc*64 + ct*16 + m;
        float mean = Mn[p], inv = Iv[p];
        long long rowb = ((long long)b*HW + n0 + p)*1280 + br*256;
        #pragma unroll
        for (int ms = 0; ms < 4; ms++){
            s4v o4;
            #pragma unroll
            for (int r = 0; r < 4; r++){
                int c = wr*64 + ms*16 + q*4 + r;
                float h = Gs[c]*((acc[ms][ct][r] - mean)*inv) + Bts[c];
                o4[r] = (short)f2bf(gelu_f(h));
            }
            *(s4v*)(catT + rowb + wr*64 + ms*16 + q*4) = o4;
        }
    }
}

// ---------------- fused 1x1-conv (MFMA) + LN + GELU, 512 thr (proj) — pipelined dbuf DMA ----------------
__global__ __launch_bounds__(512)
void k_branch1(const unsigned short* __restrict__ A, int K,
               const unsigned short* __restrict__ BT,
               const float* __restrict__ g, const float* __restrict__ beta,
               unsigned short* __restrict__ outT, int outPitch, int colOff){
    int b = blockIdx.y, n0 = blockIdx.x*32;
    const unsigned short* BTb = BT + (long long)b*HW*K;
    __shared__ __align__(16) unsigned short As[2][256*64];  // 64 KB
    __shared__ __align__(16) unsigned short Bs[2][32*64];   // 8 KB
    __shared__ float Psum[8][32], Psq[8][32], Mn[32], Iv[32];
    __shared__ float Gs[256], Bts[256];
    int t = threadIdx.x, w = t>>6, lane = t&63, m = lane&15, q = lane>>4;
    int rl8 = lane>>3, gch = (lane&7) ^ rl8, rsw = m&7;
    if (t < 256){ Gs[t] = g[t]; Bts[t] = beta[t]; }
    f4v acc[2][2];
    #pragma unroll
    for (int ms = 0; ms < 2; ms++)
        #pragma unroll
        for (int ct = 0; ct < 2; ct++){ f4v z = {0.f,0.f,0.f,0.f}; acc[ms][ct] = z; }
    const int NSt = K >> 6;                               // 20 for K=1280
    auto issue = [&](int s, int buf){
        int k0 = s*64;
        #pragma unroll
        for (int i = 0; i < 4; i++){
            int ar = w*32 + i*8;
            lds_dma16(A + (long long)(ar + rl8)*K + k0 + gch*8, &As[buf][ar*64]);
        }
        if (w < 4)
            lds_dma16(BTb + (long long)(n0 + w*8 + rl8)*K + k0 + gch*8, &Bs[buf][w*8*64]);
    };
    issue(0, 0);
    for (int s = 0; s < NSt; ++s){
        int cur = s & 1;
        if (s+1 < NSt){
            issue(s+1, cur^1);                            // prefetch into other buffer
            if (w < 4) asm volatile("s_waitcnt vmcnt(5)" ::: "memory");
            else       asm volatile("s_waitcnt vmcnt(4)" ::: "memory");
        } else {
            asm volatile("s_waitcnt vmcnt(0)" ::: "memory");
        }
        __builtin_amdgcn_s_barrier();                     // publish B(s) (no vmcnt drain)
        __builtin_amdgcn_sched_barrier(0);
        const unsigned short* Ac = &As[cur][0];
        const unsigned short* Bc = &Bs[cur][0];
        #pragma unroll
        for (int ks = 0; ks < 2; ks++){
            s8v bfr[2];
            #pragma unroll
            for (int ct = 0; ct < 2; ct++)
                bfr[ct] = *(const s8v*)&Bc[(ct*16 + m)*64 + ((q + 4*ks) ^ rsw)*8];
            #pragma unroll
            for (int ms = 0; ms < 2; ms++){
                s8v afr = *(const s8v*)&Ac[(w*32 + ms*16 + m)*64 + ((q + 4*ks) ^ rsw)*8];
                #pragma unroll
                for (int ct = 0; ct < 2; ct++)
                    acc[ms][ct] = __builtin_amdgcn_mfma_f32_16x16x32_bf16(afr, bfr[ct], acc[ms][ct], 0,0,0);
            }
        }
        __builtin_amdgcn_s_barrier();                     // buf[cur] reads done before s+2 reuses it
        __builtin_amdgcn_sched_barrier(0);
    }
    __syncthreads();
    ln_epi32(acc, b, n0, w, lane, m, q, t, Gs, Bts, Psum, Psq, Mn, Iv, outT, outPitch, colOff);
}

// ---------------- conv1 (M=128) MFMA, 256 thr, N=32, Kstage=64 — pipelined dbuf DMA ----------------
__global__ __launch_bounds__(256)
void k_conv1m(const unsigned short* __restrict__ A,      // [128][256] bf16
              const unsigned short* __restrict__ BT,     // [b][HW][256] bf16
              const float* __restrict__ bias,
              unsigned short* __restrict__ outT,         // [b][HW][128] bf16
              unsigned short* __restrict__ outC,         // [b][128][HW] bf16 or null
              float* __restrict__ outF){                 // [b][128][HW] f32 or null
    int b = blockIdx.y, n0 = blockIdx.x*32;
    const unsigned short* BTb = BT + (long long)b*HW*256;
    __shared__ __align__(16) unsigned short As[2][128*64];  // 32 KB
    __shared__ __align__(16) unsigned short Bs[2][32*64];   // 8 KB
    int t = threadIdx.x, w = t>>6, lane = t&63, m = lane&15, q = lane>>4;
    int rl8 = lane>>3, gch = (lane&7) ^ rl8, rsw = m&7;
    f4v acc[2][2];
    #pragma unroll
    for (int ms = 0; ms < 2; ms++)
        #pragma unroll
        for (int ct = 0; ct < 2; ct++){ f4v z = {0.f,0.f,0.f,0.f}; acc[ms][ct] = z; }
    auto issue = [&](int s, int buf){                     // 5 DMA/wave: 4 A + 1 B
        int k0 = s*64;
        #pragma unroll
        for (int i = 0; i < 4; i++){
            int ar = w*32 + i*8;
            lds_dma16(A + (long long)(ar + rl8)*256 + k0 + gch*8, &As[buf][ar*64]);
        }
        lds_dma16(BTb + (long long)(n0 + w*8 + rl8)*256 + k0 + gch*8, &Bs[buf][w*8*64]);
    };
    issue(0, 0);
    for (int s = 0; s < 4; ++s){
        int cur = s & 1;
        if (s+1 < 4){
            issue(s+1, cur^1);                            // prefetch into other buffer
            asm volatile("s_waitcnt vmcnt(5)" ::: "memory");  // stage-s's 5 done; s+1 in flight
        } else {
            asm volatile("s_waitcnt vmcnt(0)" ::: "memory");
        }
        __builtin_amdgcn_s_barrier();                     // publish stage s (no drain)
        __builtin_amdgcn_sched_barrier(0);
        const unsigned short* Ac = &As[cur][0];
        const unsigned short* Bc = &Bs[cur][0];
        #pragma unroll
        for (int ks = 0; ks < 2; ks++){
            s8v bfr[2];
            #pragma unroll
            for (int ct = 0; ct < 2; ct++)
                bfr[ct] = *(const s8v*)&Bc[(ct*16 + m)*64 + ((q + 4*ks) ^ rsw)*8];
            #pragma unroll
            for (int ms = 0; ms < 2; ms++){
                s8v afr = *(const s8v*)&Ac[(w*32 + ms*16 + m)*64 + ((q + 4*ks) ^ rsw)*8];
                #pragma unroll
                for (int ct = 0; ct < 2; ct++)
                    acc[ms][ct] = __builtin_amdgcn_mfma_f32_16x16x32_bf16(afr, bfr[ct], acc[ms][ct], 0,0,0);
            }
        }
        __builtin_amdgcn_s_barrier();                     // buf[cur] reads done before s+2 reuses it
        __builtin_amdgcn_sched_barrier(0);
    }
    #pragma unroll
    for (int ct = 0; ct < 2; ct++){
        int p = n0 + ct*16 + m;
        #pragma unroll
        for (int ms = 0; ms < 2; ms++){
            s4v o4;
            float vals[4];
            #pragma unroll
            for (int r = 0; r < 4; r++){
                int c = w*32 + ms*16 + q*4 + r;
                vals[r] = acc[ms][ct][r] + bias[c];
                o4[r] = (short)f2bf(vals[r]);
            }
            *(s4v*)(outT + ((long long)b*HW + p)*128 + w*32 + ms*16 + q*4) = o4;
            if (outC){
                #pragma unroll
                for (int r = 0; r < 4; r++){
                    int c = w*32 + ms*16 + q*4 + r;
                    outC[((long long)b*128 + c)*HW + p] = (unsigned short)o4[r];
                }
            }
            if (outF){
                #pragma unroll
                for (int r = 0; r < 4; r++){
                    int c = w*32 + ms*16 + q*4 + r;
                    outF[((long long)b*128 + c)*HW + p] = vals[r];
                }
            }
        }
    }
}

// ---------------- attention pass 1 (split-j): DMA-staged dbuf Ps, counted vmcnt ----------------
// Ps: 64x128 pitch, chunk16 swizzle LDS[r][c] = G[r][c ^ (r&15)], read c = (q+4ks)^m
// (byte-identical staging/read pattern to k_attn_apply2's Qks — proven bit-exact, conflict-free).
__global__ __launch_bounds__(256)
void k_attn_stats3(const unsigned short* __restrict__ QT,
                   const unsigned short* __restrict__ PT,
                   float* __restrict__ lpart){
    int b = blockIdx.z, jc = blockIdx.y, k0 = blockIdx.x * 128;
    const unsigned short* QTb = QT + (long long)b * HW * CO;
    const unsigned short* PTb = PT + (long long)b * HW * CO;
    __shared__ __align__(16) unsigned short Ps[2][64*128];   // 32 KB dbuf
    int t = threadIdx.x;
    int w = t >> 6, lane = t & 63, m = lane & 15, q = lane >> 4;
    int rl4 = lane >> 4;                                  // row within a 4-row DMA group
    s8v a[2][4];
    #pragma unroll
    for (int kh = 0; kh < 2; kh++)
        #pragma unroll
        for (int ks = 0; ks < 4; ks++)
            a[kh][ks] = *(const s8v*)(QTb + (long long)(k0 + kh*64 + w*16 + m) * CO + q*8 + ks*32);
    float rl[2][4];
    #pragma unroll
    for (int kh = 0; kh < 2; kh++)
        #pragma unroll
        for (int r = 0; r < 4; r++) rl[kh][r] = 0.f;
    const float scale = 0.015625f;           // 1/sqrt(4096)
    int jbase = jc * 1024;
    auto issue = [&](int jt, int buf){                    // 4 DMA/wave, wave w stages rows w*16..+15
        #pragma unroll
        for (int i = 0; i < 4; i++){
            int rowb = w*16 + i*4;
            int gch = (lane & 15) ^ ((rowb & 15) + rl4);
            lds_dma16(PTb + (long long)(jbase + jt*64 + rowb + rl4)*CO + gch*8, &Ps[buf][rowb*128]);
        }
    };
    issue(0, 0);
    for (int jt = 0; jt < 16; jt++){
        int cur = jt & 1;
        if (jt+1 < 16){
            issue(jt+1, cur^1);                           // prefetch into other buffer
            asm volatile("s_waitcnt vmcnt(4)" ::: "memory");  // stage-jt's 4 done; jt+1 in flight
        } else {
            asm volatile("s_waitcnt vmcnt(0)" ::: "memory");
        }
        __builtin_amdgcn_s_barrier();                     // publish stage jt (no drain)
        __builtin_amdgcn_sched_barrier(0);
        #pragma unroll
        for (int kh = 0; kh < 2; kh++){
            float sv[4][4];
            #pragma unroll
            for (int ct = 0; ct < 4; ct++){
                f4v acc = {0.f,0.f,0.f,0.f};
                #pragma unroll
                for (int ks = 0; ks < 4; ks++){
                    s8v bv = *(const s8v*)&Ps[cur][(ct*16 + m)*128 + ((q + 4*ks) ^ m)*8];
                    acc = __builtin_amdgcn_mfma_f32_16x16x32_bf16(a[kh][ks], bv, acc, 0, 0, 0);
                }
                #pragma unroll
                for (int r = 0; r < 4; r++) sv[ct][r] = acc[r] * scale;
            }
            #pragma unroll
            for (int r = 0; r < 4; r++){
                float se = __expf(sv[0][r]) + __expf(sv[1][r])
                         + __expf(sv[2][r]) + __expf(sv[3][r]);
                #pragma unroll
                for (int msk = 1; msk < 16; msk <<= 1) se += __shfl_xor(se, msk);
                rl[kh][r] += se;
            }
        }
        __builtin_amdgcn_s_barrier();                     // buf[cur] reads done before jt+2 reuses it
        __builtin_amdgcn_sched_barrier(0);
    }
    if (m == 0){
        #pragma unroll
        for (int kh = 0; kh < 2; kh++)
            #pragma unroll
            for (int r = 0; r < 4; r++){
                int k = k0 + kh*64 + w*16 + q*4 + r;
                lpart[(long long)jc * (NB*HW) + (long long)b*HW + k] = rl[kh][r];
            }
    }
}

// ---------------- attention pass 2 (split-k x2): wave-private DMA pipeline, counted vmcnt ----------------
__global__ __launch_bounds__(256)
void k_attn_apply2(const unsigned short* __restrict__ QT,
                   const unsigned short* __restrict__ PT,
                   const unsigned short* __restrict__ Pb,
                   const float* __restrict__ lpart,
                   float* __restrict__ Lp){
    int b = blockIdx.z, kc = blockIdx.y, j0 = blockIdx.x * 64;
    const unsigned short* QTb = QT + (long long)b * HW * CO;
    const unsigned short* PTb = PT + (long long)b * HW * CO;
    const unsigned short* Pbb = Pb + (long long)b * CO * HW;
    __shared__ __align__(16) unsigned short Qks[64*128];  // 16 KB
    __shared__ __align__(16) unsigned short Pcs[128*64];  // 16 KB
    __shared__ unsigned short Et[64][72];
    __shared__ float Il[2048];
    int t = threadIdx.x;
    int w = t >> 6, lane = t & 63, m = lane & 15, q = lane >> 4;
    int kbase = kc * 2048;
    int rl4 = lane >> 4;                                  // Qks DMA: row within 4-row group
    int rl8 = lane >> 3;                                  // Pcs DMA: row within 8-row group
    int gch8 = (lane & 7) ^ rl8;                          // Pcs source chunk
    {   // fused stat combine (plain sum, no-max): Il for this block's k-range
        #pragma unroll
        for (int r = 0; r < 8; r++){
            int kl = t*8 + r;
            long long gi = (long long)b*HW + kbase + kl;
            float l = lpart[gi] + lpart[gi+16384] + lpart[gi+32768] + lpart[gi+49152];
            Il[kl] = 1.f / l;
        }
    }
    {   // stage PT j-tile into Qks (4 issues/wave) then Pcs(kt=0) (4 issues/wave)
        #pragma unroll
        for (int i = 0; i < 4; i++){
            int rowb = w*16 + i*4;
            int gch = (lane & 15) ^ ((rowb & 15) + rl4);
            lds_dma16(PTb + (long long)(j0 + rowb + rl4)*CO + gch*8, &Qks[rowb*128]);
        }
        #pragma unroll
        for (int i = 0; i < 4; i++){
            int rowb = w*32 + i*8;
            lds_dma16(Pbb + (long long)(rowb + rl8)*HW + kbase + gch8*8, &Pcs[rowb*64]);
        }
    }
    asm volatile("s_waitcnt vmcnt(4) lgkmcnt(0)" ::: "memory");  // PT done; Il written; Pcs(0) in flight
    __builtin_amdgcn_s_barrier();                                // publish PT + Il
    __builtin_amdgcn_sched_barrier(0);
    s8v bj[4][4];
    #pragma unroll
    for (int ct = 0; ct < 4; ct++)
        #pragma unroll
        for (int ks = 0; ks < 4; ks++)
            bj[ct][ks] = *(const s8v*)&Qks[(ct*16 + m)*128 + ((q + 4*ks) ^ m)*8];
    asm volatile("s_waitcnt lgkmcnt(0)" ::: "memory");           // bj in regs
    __builtin_amdgcn_s_barrier();                                // all waves done reading PT tile
    __builtin_amdgcn_sched_barrier(0);
    {   // Qks <- QT k-tile for kt=0
        #pragma unroll
        for (int i = 0; i < 4; i++){
            int rowb = w*16 + i*4;
            int gch = (lane & 15) ^ ((rowb & 15) + rl4);
            lds_dma16(QTb + (long long)(kbase + rowb + rl4)*CO + gch*8, &Qks[rowb*128]);
        }
    }
    f4v accL[2][4];
    #pragma unroll
    for (int mt = 0; mt < 2; mt++)
        #pragma unroll
        for (int ct = 0; ct < 4; ct++){ f4v z = {0.f,0.f,0.f,0.f}; accL[mt][ct] = z; }
    const float scale = 0.015625f;
    for (int kt = 0; kt < 32; kt++){
        int k0 = kbase + kt*64;
        // wait this wave's Qks(kt) (oldest); Pcs stays in flight (kt=0: queue order differs -> drain)
        if (kt == 0) asm volatile("s_waitcnt vmcnt(0)" ::: "memory");
        else         asm volatile("s_waitcnt vmcnt(4)" ::: "memory");
        __builtin_amdgcn_sched_barrier(0);
        // ---- QK phase (own Qks rows) ----
        s8v aS[4];
        #pragma unroll
        for (int ks = 0; ks < 4; ks++)
            aS[ks] = *(const s8v*)&Qks[(w*16 + m)*128 + ((q + 4*ks) ^ m)*8];
        float il[4];
        #pragma unroll
        for (int r = 0; r < 4; r++) il[r] = Il[kt*64 + w*16 + q*4 + r];
        #pragma unroll
        for (int ct = 0; ct < 4; ct++){
            f4v s = {0.f,0.f,0.f,0.f};
            #pragma unroll
            for (int ks = 0; ks < 4; ks++)
                s = __builtin_amdgcn_mfma_f32_16x16x32_bf16(aS[ks], bj[ct][ks], s, 0, 0, 0);
            s4v e4;
            #pragma unroll
            for (int r = 0; r < 4; r++)
                e4[r] = (short)f2bf(__expf(s[r]*scale) * il[r]);
            *(s4v*)&Et[ct*16 + m][w*16 + q*4] = e4;
        }
        // prefetch own Qks rows for kt+1 (aS consumed via MFMA lgkm waits)
        if (kt+1 < 32){
            #pragma unroll
            for (int i = 0; i < 4; i++){
                int rowb = w*16 + i*4;
                int gch = (lane & 15) ^ ((rowb & 15) + rl4);
                lds_dma16(QTb + (long long)(k0 + 64 + rowb + rl4)*CO + gch*8, &Qks[rowb*128]);
            }
        }
        asm volatile("s_waitcnt lgkmcnt(0)" ::: "memory");   // Et committed
        __builtin_amdgcn_s_barrier();                        // publish Et (DMAs stay in flight)
        __builtin_amdgcn_sched_barrier(0);
        // wait this wave's Pcs(kt) (oldest); Qks(kt+1) stays in flight
        asm volatile("s_waitcnt vmcnt(4)" ::: "memory");
        __builtin_amdgcn_sched_barrier(0);
        // ---- PV phase (own Pcs rows, shared Et) ----
        s8v aP[2][2];
        #pragma unroll
        for (int mt = 0; mt < 2; mt++)
            #pragma unroll
            for (int ks2 = 0; ks2 < 2; ks2++)
                aP[mt][ks2] = *(const s8v*)&Pcs[(w*32 + mt*16 + m)*64 + ((q + 4*ks2) ^ (m&7))*8];
        #pragma unroll
        for (int ct = 0; ct < 4; ct++){
            s8v bE0 = *(const s8v*)&Et[ct*16 + m][q*8];
            s8v bE1 = *(const s8v*)&Et[ct*16 + m][q*8 + 32];
            #pragma unroll
            for (int mt = 0; mt < 2; mt++){
                accL[mt][ct] = __builtin_amdgcn_mfma_f32_16x16x32_bf16(aP[mt][0], bE0, accL[mt][ct], 0, 0, 0);
                accL[mt][ct] = __builtin_amdgcn_mfma_f32_16x16x32_bf16(aP[mt][1], bE1, accL[mt][ct], 0, 0, 0);
            }
        }
        // prefetch own Pcs rows for kt+1 (aP consumed)
        if (kt+1 < 32){
            #pragma unroll
            for (int i = 0; i < 4; i++){
                int rowb = w*32 + i*8;
                lds_dma16(Pbb + (long long)(rowb + rl8)*HW + k0 + 64 + gch8*8, &Pcs[rowb*64]);
            }
        }
        __builtin_amdgcn_s_barrier();                        // Et(kt) reads done before Et(kt+1) writes
        __builtin_amdgcn_sched_barrier(0);
    }
    float* Lpb = Lp + ((long long)(kc*NB + b) * CO) * HW;
    #pragma unroll
    for (int mt = 0; mt < 2; mt++)
        #pragma unroll
        for (int ct = 0; ct < 4; ct++)
            #pragma unroll
            for (int r = 0; r < 4; r++){
                int c = w*32 + mt*16 + q*4 + r;
                Lpb[(long long)c*HW + j0 + ct*16 + m] = accL[mt][ct][r];
            }
}

// ---------------- fused: O = xa + sum(Lp) -> bf16 B-tile -> conv2 -> out f32 (DMA A-staging) ----------------
__global__ __launch_bounds__(256)
void k_outfused(const unsigned short* __restrict__ A,    // w_c2 [256][128] bf16
                const float* __restrict__ Lp, const float* __restrict__ xa,
                const float* __restrict__ bias, float* __restrict__ out){
    int b = blockIdx.y, j0 = blockIdx.x*32;
    __shared__ unsigned short Bs[32][136];
    __shared__ __align__(16) char pool[256*68*2];   // phase1: Bsf[128][33] f32; phase2: As[256*64] bf16
    int t = threadIdx.x;
    // phase 1: O tile f32 = xa + 2 partials (coalesced c-rows)
    {
        float* Bsf = (float*)pool;
        int c = t>>1, jh = t&1;
        long long base = ((long long)b*CO + c)*HW + j0 + jh*16;
        const long long csz = (long long)NB*CO*HW;
        float v[16];
        #pragma unroll
        for (int r = 0; r < 16; r++) v[r] = xa[base + r];
        #pragma unroll
        for (int pidx = 0; pidx < 2; pidx++){
            const float* src = Lp + pidx*csz + base;
            #pragma unroll
            for (int r = 0; r < 16; r++) v[r] += src[r];
        }
        #pragma unroll
        for (int r = 0; r < 16; r++) Bsf[c*33 + jh*16 + r] = v[r];
    }
    __syncthreads();
    // transpose to bf16 B-tile [j][c]
    {
        const float* Bsf = (const float*)pool;
        int j = t>>3, cs = t&7;
        #pragma unroll
        for (int r = 0; r < 16; r++){
            int c = cs*16 + r;
            Bs[j][c] = f2bf(Bsf[c*33 + j]);
        }
    }
    __syncthreads();
    // phase 2: GEMM M=256 x N=32 x K=128, A staged via DMA (pitch 64, swizzled)
    unsigned short* As = (unsigned short*)pool;
    int w = t>>6, lane = t&63, m = lane&15, q = lane>>4;
    int rl8 = lane>>3, gch = (lane&7) ^ rl8, rsw = m&7;
    f4v acc[4][2];
    #pragma unroll
    for (int ms = 0; ms < 4; ms++)
        #pragma unroll
        for (int ct = 0; ct < 2; ct++){ f4v z = {0.f,0.f,0.f,0.f}; acc[ms][ct] = z; }
    for (int k0 = 0; k0 < 128; k0 += 64){
        __syncthreads();                                  // prior reads of pool/As done
        #pragma unroll
        for (int i = 0; i < 8; i++){
            int ar = w*64 + i*8;
            lds_dma16(A + (long long)(ar + rl8)*128 + k0 + gch*8, &As[ar*64]);
        }
        __syncthreads();                                  // vmcnt(0) drained -> visible
        #pragma unroll
        for (int ks = 0; ks < 2; ks++){
            s8v bfr[2];
            #pragma unroll
            for (int ct = 0; ct < 2; ct++) bfr[ct] = *(const s8v*)&Bs[ct*16+m][k0 + ks*32 + q*8];
            #pragma unroll
            for (int ms = 0; ms < 4; ms++){
                s8v afr = *(const s8v*)&As[(w*64 + ms*16 + m)*64 + ((q + 4*ks) ^ rsw)*8];
                #pragma unroll
                for (int ct = 0; ct < 2; ct++)
                    acc[ms][ct] = __builtin_amdgcn_mfma_f32_16x16x32_bf16(afr, bfr[ct], acc[ms][ct], 0,0,0);
            }
        }
    }
    #pragma unroll
    for (int ct = 0; ct < 2; ct++){
        int p = j0 + ct*16 + m;
        #pragma unroll
        for (int ms = 0; ms < 4; ms++)
            #pragma unroll
            for (int r = 0; r < 4; r++){
                int c = w*64 + ms*16 + q*4 + r;
                out[((long long)b*256 + c)*HW + p] = acc[ms][ct][r] + bias[c];
            }
    }
}

extern "C" void kernel_launch(void* const* d_in, const int* in_sizes, int n_in,
                              void* d_out, int out_size, void* d_ws, size_t ws_size,
                              hipStream_t stream) {
    const float* x       = (const float*)d_in[0];
    const float* conv1_w = (const float*)d_in[1];
    const float* conv1_b = (const float*)d_in[2];
    const float* conv2_w = (const float*)d_in[3];
    const float* conv2_b = (const float*)d_in[4];
    const float* cw_w1   = (const float*)d_in[5];
    const float* cw_b1   = (const float*)d_in[6];
    const float* cw_g    = (const float*)d_in[7];
    const float* cw_bt   = (const float*)d_in[8];
    const float* cw_w2   = (const float*)d_in[9];
    const float* cw_b2   = (const float*)d_in[10];
    const float* a0_w    = (const float*)d_in[11];
    const float* a0_g    = (const float*)d_in[12];
    const float* a0_b    = (const float*)d_in[13];
    const float* a1_w    = (const float*)d_in[14];
    const float* a1_g    = (const float*)d_in[15];
    const float* a1_b    = (const float*)d_in[16];
    const float* a2_w    = (const float*)d_in[17];
    const float* a2_g    = (const float*)d_in[18];
    const float* a2_b    = (const float*)d_in[19];
    const float* a3_w    = (const float*)d_in[20];
    const float* a3_g    = (const float*)d_in[21];
    const float* a3_b    = (const float*)d_in[22];
    const float* ap_w    = (const float*)d_in[23];
    const float* ap_g    = (const float*)d_in[24];
    const float* ap_b    = (const float*)d_in[25];
    const float* pj_w    = (const float*)d_in[26];
    const float* pj_g    = (const float*)d_in[27];
    const float* pj_b    = (const float*)d_in[28];
    float* out = (float*)d_out;

    // ---- workspace layout ----
    float* ws    = (float*)d_ws;
    float* avg   = ws;                  // 1024
    float* mx    = ws + 1024;           // 1024
    float* sv    = ws + 2048;           // 1024
    float* gp    = ws + 3072;           // 1024
    float* zbuf  = ws + 4096;           // 256 f32 zero-page for OOB DMA
    float* xa    = ws + 37888;          // 2,097,152
    float* lpart = xa + 2097152;        // 65536
    unsigned short* sb = (unsigned short*)(ws + 4232192);
    unsigned short* xT    = sb;                    // 4,194,304
    unsigned short* xcT   = sb + 4194304;          // 4,194,304
    unsigned short* catT  = sb + 8388608;          // 20,971,520
    unsigned short* projT = sb + 29360128;         // 4,194,304
    unsigned short* P_bf  = sb + 33554432;         // 2,097,152
    unsigned short* PT_bf = sb + 35651584;         // 2,097,152
    unsigned short* QT_bf = sb + 37748736;         // 2,097,152
    unsigned short* w_c1  = sb + 41943040;         // 32768
    unsigned short* w_a0  = sb + 41975808;         // 65536
    unsigned short* w_pj  = sb + 42041344;         // 327680
    unsigned short* w_c2  = sb + 42369024;         // 32768
    unsigned short* w_d3  = sb + 42401792;         // 589824
    unsigned short* w_d6  = sb + 42991616;         // 589824
    unsigned short* w_d9  = sb + 43581440;         // 589824
    float* Lp = (float*)catT;           // alias: catT dead after proj (16.8MB in 42MB region)

    // ---- rowstats + all weight casts (one launch) ----
    k_pre<<<dim3(9728), 256, 0, stream>>>(x, avg, mx,
                                          conv1_w, a0_w, pj_w, conv2_w, a1_w, a2_w, a3_w,
                                          w_c1, w_a0, w_pj, w_c2, w_d3, w_d6, w_d9);
    k_cw<<<dim3(NB), 256, 0, stream>>>(avg, mx, cw_w1, cw_b1, cw_g, cw_bt, cw_w2, cw_b2, sv, gp, zbuf);

    // ---- x -> xT bf16 and xcT ----
    k_xT<<<dim3(64, 4, NB), 256, 0, stream>>>(x, sv, xT, xcT);

    // ---- x1 = conv1(x)+b -> P_bf/PT_bf ----
    k_conv1m<<<dim3(128, NB), 256, 0, stream>>>(w_c1, xT, conv1_b, PT_bf, P_bf, nullptr);

    // ---- ASPP: a0 + 3 dilated convs + pool/bcast in ONE launch (N=128, DMA staging) ----
    k_aspp<<<dim3(32, 5, NB), 512, 0, stream>>>(w_a0, w_d3, w_d6, w_d9, xcT,
                                                a0_g, a0_b, a1_g, a1_b, a2_g, a2_b, a3_g, a3_b,
                                                gp, ap_w, ap_g, ap_b, zbuf, catT);

    // ---- proj = GELU(LN(conv1x1(cat))) -> projT bf16 (pipelined dbuf DMA) ----
    k_branch1<<<dim3(128, NB), 512, 0, stream>>>(w_pj, 1280, catT, pj_g, pj_b, projT, 256, 0);

    // ---- xa = conv1(proj)+b -> xa f32 + QT_bf ----
    k_conv1m<<<dim3(128, NB), 256, 0, stream>>>(w_c1, projT, conv1_b, QT_bf, nullptr, xa);

    // ---- attention (no-max softmax; comb fused into apply; kc-split = 2; counted-vmcnt both) ----
    k_attn_stats3<<<dim3(32, 4, NB), 256, 0, stream>>>(QT_bf, PT_bf, lpart);
    k_attn_apply2<<<dim3(64, 2, NB), 256, 0, stream>>>(QT_bf, PT_bf, P_bf, lpart, Lp);

    // ---- out = conv2(xa + sum Lp) + b (fused) ----
    k_outfused<<<dim3(128, NB), 256, 0, stream>>>(w_c2, Lp, xa, conv2_b, out);

    (void)in_sizes; (void)n_in; (void)out_size; (void)ws_size;
}